// Round 7
// baseline (144.617 us; speedup 1.0000x reference)
//
#include <hip/hip_runtime.h>
#include <hip/hip_bf16.h>

typedef __hip_bfloat16 bf16;
typedef __attribute__((ext_vector_type(8))) short short8;
typedef __attribute__((ext_vector_type(4))) short short4v;
typedef __attribute__((ext_vector_type(4))) float f32x4;

#define N_      4
#define CI_     128
#define R_      64
#define A_      64
#define HEADS_  4
#define HD_     16
#define H_      48
#define W_      48
#define P_      (H_ * W_)      // 2304
#define HP_     50
#define PP_     (HP_ * HP_)    // 2500
#define HK_     46
#define DK_     (HK_ * HK_)    // 2116
#define M_ALL   448            // 7 conv sets x 64
#define KPAD_   2144           // 134 * 16
#define VPAD_   2176           // KPAD_ + 32 slack
#define WCONV_  516096         // 448*1152
#define WGATE_  16384          // 256*64
#define BPAD_   136            // 128 + 8 LDS pad

__device__ __forceinline__ float sigmoidf_(float x) { return 1.f / (1.f + __expf(-x)); }
__device__ __forceinline__ float tanh_fast(float x) {
    float e = __expf(-2.f * fabsf(x));
    float t = (1.f - e) / (1.f + e);
    return copysignf(t, x);
}
template<bool BF>
__device__ __forceinline__ float ldv(const void* p, size_t i) {
    if (BF) return __bfloat162float(((const bf16*)p)[i]);
    else    return ((const float*)p)[i];
}
__device__ __forceinline__ unsigned short f2b(float f) {
    bf16 b = __float2bfloat16(f);
    return *reinterpret_cast<unsigned short*>(&b);
}

// ---------------------------------------------------------------------------
// K0: dtype detect (bf16-packed vs fp32) from W_x bit patterns.
// ---------------------------------------------------------------------------
__global__ void k_detect(const unsigned* __restrict__ wx, unsigned* __restrict__ flag) {
    if (threadIdx.x == 0 && blockIdx.x == 0) {
        int votes = 0;
        for (int i = 0; i < 64; i++) {
            unsigned e = (wx[i] >> 7) & 0xFFu;
            votes += (e >= 100u && e <= 134u) ? 1 : 0;
        }
        *flag = (votes >= 48) ? 1u : 0u;   // 1 = bf16, 0 = fp32
    }
}

// ---------------------------------------------------------------------------
// K1a: proj_x 1x1 conv into transposed bf16 xh_t[n][pp][ci], channels 0..63.
// ---------------------------------------------------------------------------
template<bool BF>
__device__ void build_x_body(const void* __restrict__ x_in, const void* __restrict__ W_x,
                             const void* __restrict__ b_x, unsigned short* __restrict__ xh_t) {
    int idx = blockIdx.x * 256 + threadIdx.x;
    if (idx >= N_ * 16 * 1152) return;
    int pp  = idx % 1152;
    int cog = (idx / 1152) & 15;
    int n   = idx / (1152 * 16);
    int p0 = pp * 2;
    int co0 = cog * 4;

    float acc[4][2];
    #pragma unroll
    for (int j = 0; j < 4; j++) { float b = ldv<BF>(b_x, co0 + j); acc[j][0] = b; acc[j][1] = b; }

    size_t xb = (size_t)n * 128 * P_ + p0;
    #pragma unroll 4
    for (int ci = 0; ci < 128; ci++) {
        float x0 = ldv<BF>(x_in, xb + (size_t)ci * P_);
        float x1 = ldv<BF>(x_in, xb + (size_t)ci * P_ + 1);
        #pragma unroll
        for (int j = 0; j < 4; j++) {
            float w = ldv<BF>(W_x, (co0 + j) * 128 + ci);
            acc[j][0] += w * x0;
            acc[j][1] += w * x1;
        }
    }
    #pragma unroll
    for (int pi = 0; pi < 2; pi++) {
        int p = p0 + pi;
        int py = p / W_ + 1, px = p % W_ + 1;
        short4v v;
        #pragma unroll
        for (int j = 0; j < 4; j++) v[j] = (short)f2b(acc[j][pi]);
        *reinterpret_cast<short4v*>(xh_t + ((size_t)n * PP_ + py * HP_ + px) * 128 + co0) = v;
    }
}
__global__ void k_build_x(const void* x_in, const void* W_x, const void* b_x,
                          unsigned short* xh_t, const unsigned* flag) {
    if (*flag) build_x_body<true>(x_in, W_x, b_x, xh_t);
    else       build_x_body<false>(x_in, W_x, b_x, xh_t);
}

// K1b: h into xh_t channels 64..127 (8 channels per thread).
template<bool BF>
__device__ void copy_h_body(const void* __restrict__ h, unsigned short* __restrict__ xh_t) {
    int idx = blockIdx.x * 256 + threadIdx.x;
    if (idx >= N_ * 8 * P_) return;
    int p  = idx % P_;
    int cg = (idx / P_) & 7;
    int n  = idx / (P_ * 8);
    int py = p / W_ + 1, px = p % W_ + 1;
    short8 v;
    #pragma unroll
    for (int j = 0; j < 8; j++)
        v[j] = (short)f2b(ldv<BF>(h, ((size_t)n * R_ + cg * 8 + j) * P_ + p));
    *reinterpret_cast<short8*>(xh_t + ((size_t)n * PP_ + py * HP_ + px) * 128 + 64 + cg * 8) = v;
}
__global__ void k_copy_h(const void* h, unsigned short* xh_t, const unsigned* flag) {
    if (*flag) copy_h_body<true>(h, xh_t);
    else       copy_h_body<false>(h, xh_t);
}

// ---------------------------------------------------------------------------
// K1c: weights -> wt[448][9][128] bf16 (conv) + wg[256][64] bf16 (gate 1x1)
// ---------------------------------------------------------------------------
struct WPtrs { const void* p[11]; };
template<bool BF>
__device__ void build_wt_body(WPtrs wp, unsigned short* __restrict__ wt) {
    int idx = blockIdx.x * 256 + threadIdx.x;
    if (idx < WCONV_) {
        int ci  = idx % 128;
        int tap = (idx / 128) % 9;
        int m   = idx / 1152;
        int set = m >> 6, co = m & 63;
        wt[idx] = f2b(ldv<BF>(wp.p[set], (size_t)(co * 128 + ci) * 9 + tap));
    } else if (idx < WCONV_ + WGATE_) {
        int j  = idx - WCONV_;
        int ca = j & 63;
        int m  = j >> 6;          // gate*64 + r
        int gate = m >> 6, r = m & 63;
        wt[idx] = f2b(ldv<BF>(wp.p[7 + gate], r * 64 + ca));
    }
}
__global__ void k_build_wt(WPtrs wp, unsigned short* wt, const unsigned* flag) {
    if (*flag) build_wt_body<true>(wp, wt);
    else       build_wt_body<false>(wp, wt);
}

// ---------------------------------------------------------------------------
// K2: all seven 3x3 convs as one implicit GEMM, LDS-staged B.
// ---------------------------------------------------------------------------
__global__ __launch_bounds__(256) void k_conv_mfma(const unsigned short* __restrict__ xh_t,
                                                   const unsigned short* __restrict__ wt,
                                                   float* __restrict__ C) {
    __shared__ unsigned short Bs[3 * 50 * BPAD_];   // 40800 B
    int wid  = threadIdx.x >> 6;
    int lane = threadIdx.x & 63;
    int mg = blockIdx.x % 7;
    int y  = (blockIdx.x / 7) % 48;
    int n  = blockIdx.x / (7 * 48);
    int m0 = mg * 64 + wid * 16;
    int l15 = lane & 15;
    int kq  = lane >> 4;

    const unsigned short* src = xh_t + (size_t)n * PP_ * 128 + (size_t)y * HP_ * 128;
    for (int i = threadIdx.x; i < 2400; i += 256) {
        int r  = i / 800, e8 = i % 800;
        int px = e8 >> 4, cig = e8 & 15;
        short8 v = *reinterpret_cast<const short8*>(src + r * 6400 + e8 * 8);
        *reinterpret_cast<short8*>(Bs + (r * HP_ + px) * BPAD_ + cig * 8) = v;
    }
    __syncthreads();

    f32x4 acc[3] = {f32x4{0,0,0,0}, f32x4{0,0,0,0}, f32x4{0,0,0,0}};
    const unsigned short* Arow = wt + (size_t)(m0 + l15) * 1152 + kq * 8;

    #pragma unroll
    for (int r = 0; r < 3; r++) {
        #pragma unroll
        for (int c = 0; c < 3; c++) {
            int tap = r * 3 + c;
            short8 a8[4];
            #pragma unroll
            for (int cb = 0; cb < 4; cb++)
                a8[cb] = *reinterpret_cast<const short8*>(Arow + tap * 128 + cb * 32);
            #pragma unroll
            for (int cb = 0; cb < 4; cb++) {
                #pragma unroll
                for (int nf = 0; nf < 3; nf++) {
                    short8 b8 = *reinterpret_cast<const short8*>(
                        Bs + (size_t)(r * HP_ + c + nf * 16 + l15) * BPAD_ + cb * 32 + kq * 8);
                    acc[nf] = __builtin_amdgcn_mfma_f32_16x16x32_bf16(a8[cb], b8, acc[nf], 0, 0, 0);
                }
            }
        }
    }
    #pragma unroll
    for (int nf = 0; nf < 3; nf++) {
        int p = y * 48 + nf * 16 + l15;
        #pragma unroll
        for (int reg = 0; reg < 4; reg++) {
            int m = m0 + kq * 4 + reg;
            C[((size_t)n * M_ALL + m) * P_ + p] = acc[nf][reg];
        }
    }
}

// ---------------------------------------------------------------------------
// K2b: stage Q/K/V for MFMA attention as bf16.
// ---------------------------------------------------------------------------
#define QTOT_ (16 * 2304 * 16)
#define KTOT_ (16 * KPAD_ * 16)
#define VTOT_ (16 * 16 * VPAD_)
template<bool BF>
__device__ void stage_body(const float* __restrict__ C, const void* __restrict__ b_v,
                           unsigned short* __restrict__ Qb, unsigned short* __restrict__ Kb,
                           unsigned short* __restrict__ Vb) {
    int idx = blockIdx.x * 256 + threadIdx.x;
    if (idx < QTOT_) {
        int c = idx & 15, qp = (idx >> 4) % 2304, ng = idx / (2304 * 16);
        int n = ng >> 2, g = ng & 3;
        Qb[idx] = f2b(C[((size_t)n * M_ALL + g * HD_ + c) * P_ + qp]);
    } else if (idx < QTOT_ + KTOT_) {
        int i = idx - QTOT_;
        int c = i & 15, key = (i >> 4) % KPAD_, ng = i / (KPAD_ * 16);
        int n = ng >> 2, g = ng & 3;
        float v = 0.f;
        if (key < DK_)
            v = C[((size_t)n * M_ALL + 64 + g * HD_ + c) * P_ + (key / HK_ + 1) * 48 + key % HK_ + 1];
        Kb[i] = f2b(v);
    } else if (idx < QTOT_ + KTOT_ + VTOT_) {
        int i = idx - QTOT_ - KTOT_;
        int key = i % VPAD_, c = (i / VPAD_) & 15, ng = i / (VPAD_ * 16);
        int n = ng >> 2, g = ng & 3;
        float v = 0.f;
        if (key < DK_)
            v = C[((size_t)n * M_ALL + 128 + g * HD_ + c) * P_ + (key / HK_ + 1) * 48 + key % HK_ + 1]
                + ldv<BF>(b_v, g * HD_ + c);
        Vb[i] = f2b(v);
    }
}
__global__ void k_stage_qkv(const float* C, const void* b_v, unsigned short* Qb,
                            unsigned short* Kb, unsigned short* Vb, const unsigned* flag) {
    if (*flag) stage_body<true>(C, b_v, Qb, Kb, Vb);
    else       stage_body<false>(C, b_v, Qb, Kb, Vb);
}

// ---------------------------------------------------------------------------
// K3: MFMA flash attention. Preferred path: 16x16x16 bf16 MFMA (K=16 = HD):
//     QK^T C-layout [key=g4*4+r][q=l15] IS the PV B-layout [k=g4*4+j][q=l15]
//     -> P^T never leaves the lane (no shuffles, no LDS).
//     Fallback (builtin missing): round-5 16x16x32 + shfl path.
// ---------------------------------------------------------------------------
__global__ __launch_bounds__(256) void k_attn_mfma(const unsigned short* __restrict__ Qb,
                                                   const unsigned short* __restrict__ Kb,
                                                   const unsigned short* __restrict__ Vb,
                                                   unsigned short* __restrict__ a_bt) {
    int wid = threadIdx.x >> 6;
    int lane = threadIdx.x & 63;
    int ng   = blockIdx.x & 15;
    int qblk = blockIdx.x >> 4;
    int qt   = qblk * 4 + wid;
    int l15  = lane & 15;
    int g4   = lane >> 4;

    float lp = 0.f;
    f32x4 accT;

#if __has_builtin(__builtin_amdgcn_mfma_f32_16x16x16bf16_1k)
    // B-frag (QK): Q[q=l15][ch=g4*4+j]
    short4v qfrag = *reinterpret_cast<const short4v*>(
        Qb + ((size_t)ng * 2304 + qt * 16 + l15) * 16 + g4 * 4);
    const unsigned short* Kp = Kb + ((size_t)ng * KPAD_ + l15) * 16 + g4 * 4;
    const unsigned short* Vp = Vb + ((size_t)ng * 16 + l15) * VPAD_ + g4 * 4;

    f32x4 accA = {0, 0, 0, 0}, accB = {0, 0, 0, 0};
    #pragma unroll 2
    for (int t = 0; t < KPAD_ / 16; t++) {
        // A-frag (QK): K[key=t*16+l15][ch=g4*4+j]
        short4v kfrag = *reinterpret_cast<const short4v*>(Kp + t * 256);
        f32x4 s = __builtin_amdgcn_mfma_f32_16x16x16bf16_1k(kfrag, qfrag, f32x4{0, 0, 0, 0}, 0, 0, 0);
        f32x4 p;
        short4v pb;
        #pragma unroll
        for (int r = 0; r < 4; r++) { p[r] = __expf(s[r]); pb[r] = (short)f2b(p[r]); }
        lp += p[0] + p[1] + p[2] + p[3];
        // A-frag (PV): V^T[c=l15][key=t*16+g4*4+j]; B-frag = pb (in-lane).
        short4v vfrag = *reinterpret_cast<const short4v*>(Vp + t * 16);
        if (t & 1) accB = __builtin_amdgcn_mfma_f32_16x16x16bf16_1k(vfrag, pb, accB, 0, 0, 0);
        else       accA = __builtin_amdgcn_mfma_f32_16x16x16bf16_1k(vfrag, pb, accA, 0, 0, 0);
    }
    #pragma unroll
    for (int r = 0; r < 4; r++) accT[r] = accA[r] + accB[r];
#else
    const short8 zero8 = {0, 0, 0, 0, 0, 0, 0, 0};
    const unsigned short* Qp = Qb + ((size_t)ng * 2304 + qt * 16 + l15) * 16;
    short8 qfrag8 = (g4 < 2) ? *reinterpret_cast<const short8*>(Qp + g4 * 8) : zero8;
    const unsigned short* Kp = Kb + (size_t)ng * KPAD_ * 16;
    const unsigned short* Vp = Vb + (size_t)ng * 16 * VPAD_;
    f32x4 acc = {0, 0, 0, 0};
    #pragma unroll 2
    for (int t = 0; t < KPAD_ / 16; t++) {
        short8 kfrag = *reinterpret_cast<const short8*>(Kp + (size_t)(t * 16 + l15) * 16 + g4 * 8);
        f32x4 s = __builtin_amdgcn_mfma_f32_16x16x32_bf16(kfrag, qfrag8, f32x4{0, 0, 0, 0}, 0, 0, 0);
        f32x4 p;
        #pragma unroll
        for (int r = 0; r < 4; r++) p[r] = __expf(s[r]);
        lp += p[0] + p[1] + p[2] + p[3];
        short8 bfrag;
        #pragma unroll
        for (int j = 0; j < 8; j++) {
            int srcl = ((((g4 & 1) * 2 + (j >> 2)) << 4) | l15);
            float pv = __shfl(p[j & 3], srcl);
            bfrag[j] = (g4 < 2) ? (short)f2b(pv) : (short)0;
        }
        short8 vfrag = *reinterpret_cast<const short8*>(Vp + (size_t)l15 * VPAD_ + t * 16 + g4 * 8);
        acc = __builtin_amdgcn_mfma_f32_16x16x32_bf16(vfrag, bfrag, acc, 0, 0, 0);
    }
    accT = acc;
#endif

    float l = lp + __shfl_xor(lp, 16);
    l += __shfl_xor(l, 32);
    l -= 28.f;                 // KPAD_-DK_ zero-keys contribute exp(0)=1 each
    float inv = 1.f / l;

    int n = ng >> 2, g = ng & 3;
    short4v ov;
    #pragma unroll
    for (int r = 0; r < 4; r++) ov[r] = (short)f2b(accT[r] * inv);
    *reinterpret_cast<short4v*>(a_bt + ((size_t)n * 2304 + qt * 16 + l15) * 64 + g * HD_ + g4 * 4) = ov;
}

// ---------------------------------------------------------------------------
// K3c: gate 1x1 conv (M=256, K=64) via MFMA, accumulated onto C rows 192..447.
// ---------------------------------------------------------------------------
__global__ __launch_bounds__(256) void k_gate1x1(const unsigned short* __restrict__ a_bt,
                                                 const unsigned short* __restrict__ wg,
                                                 float* __restrict__ C) {
    int wid  = threadIdx.x >> 6;
    int lane = threadIdx.x & 63;
    int mg = blockIdx.x & 3;
    int y  = (blockIdx.x >> 2) % 48;
    int n  = blockIdx.x / (4 * 48);
    int m0 = mg * 64 + wid * 16;
    int l15 = lane & 15;
    int kq  = lane >> 4;

    f32x4 acc[3] = {f32x4{0,0,0,0}, f32x4{0,0,0,0}, f32x4{0,0,0,0}};
    const unsigned short* Ar = wg + (size_t)(m0 + l15) * 64 + kq * 8;
    const unsigned short* Br = a_bt + ((size_t)n * 2304 + y * 48) * 64 + kq * 8;

    #pragma unroll
    for (int ks = 0; ks < 2; ks++) {
        short8 a8 = *reinterpret_cast<const short8*>(Ar + ks * 32);
        #pragma unroll
        for (int nf = 0; nf < 3; nf++) {
            short8 b8 = *reinterpret_cast<const short8*>(Br + (size_t)(nf * 16 + l15) * 64 + ks * 32);
            acc[nf] = __builtin_amdgcn_mfma_f32_16x16x32_bf16(a8, b8, acc[nf], 0, 0, 0);
        }
    }
    #pragma unroll
    for (int nf = 0; nf < 3; nf++) {
        int p = y * 48 + nf * 16 + l15;
        #pragma unroll
        for (int reg = 0; reg < 4; reg++) {
            int m = m0 + kq * 4 + reg;
            size_t ci = ((size_t)n * M_ALL + 192 + m) * P_ + p;
            C[ci] += acc[nf][reg];
        }
    }
}

// ---------------------------------------------------------------------------
// K4: pure pointwise LSTM. 4 pixels per thread, vectorized.
// ---------------------------------------------------------------------------
template<bool BF>
__device__ void pointwise_body(const float* __restrict__ C,
                               const void* bi, const void* bf_, const void* bg, const void* bo,
                               const void* c_in, void* __restrict__ h_out) {
    int idx = blockIdx.x * 256 + threadIdx.x;
    if (idx >= N_ * R_ * 576) return;
    int p4 = idx % 576;
    int r  = (idx / 576) & 63;
    int n  = idx / (576 * 64);
    int p0 = p4 * 4;

    const float* base = C + ((size_t)n * M_ALL + 192 + r) * P_ + p0;
    float4 vi = *reinterpret_cast<const float4*>(base);
    float4 vf = *reinterpret_cast<const float4*>(base + (size_t)64 * P_);
    float4 vg = *reinterpret_cast<const float4*>(base + (size_t)128 * P_);
    float4 vo = *reinterpret_cast<const float4*>(base + (size_t)192 * P_);
    float bii = ldv<BF>(bi, r), bff = ldv<BF>(bf_, r);
    float bgg = ldv<BF>(bg, r), boo = ldv<BF>(bo, r);

    size_t cbase = ((size_t)n * R_ + r) * P_ + p0;
    float hi[4];
    #pragma unroll
    for (int j = 0; j < 4; j++) {
        float ai = (j == 0 ? vi.x : j == 1 ? vi.y : j == 2 ? vi.z : vi.w) + bii;
        float af = (j == 0 ? vf.x : j == 1 ? vf.y : j == 2 ? vf.z : vf.w) + bff;
        float ag = (j == 0 ? vg.x : j == 1 ? vg.y : j == 2 ? vg.z : vg.w) + bgg;
        float ao = (j == 0 ? vo.x : j == 1 ? vo.y : j == 2 ? vo.z : vo.w) + boo;
        float ig = sigmoidf_(ai);
        float fg = sigmoidf_(af);
        float gg = tanh_fast(ag);
        float og = sigmoidf_(ao);
        float cn = fg * ldv<BF>(c_in, cbase + j) + ig * gg;
        hi[j] = og * tanh_fast(cn);
    }
    if (BF) {
        short4v ov;
        #pragma unroll
        for (int j = 0; j < 4; j++) ov[j] = (short)f2b(hi[j]);
        *reinterpret_cast<short4v*>((bf16*)h_out + cbase) = ov;
    } else {
        float4 ov = {hi[0], hi[1], hi[2], hi[3]};
        *reinterpret_cast<float4*>((float*)h_out + cbase) = ov;
    }
}
__global__ void k_pointwise(const float* C, const void* bi, const void* bf_,
                            const void* bg, const void* bo, const void* c_in,
                            const unsigned* flag, void* h_out) {
    if (*flag) pointwise_body<true>(C, bi, bf_, bg, bo, c_in, h_out);
    else       pointwise_body<false>(C, bi, bf_, bg, bo, c_in, h_out);
}

// ---------------------------------------------------------------------------
extern "C" void kernel_launch(void* const* d_in, const int* in_sizes, int n_in,
                              void* d_out, int out_size, void* d_ws, size_t ws_size,
                              hipStream_t stream) {
    float* ws = (float*)d_ws;
    unsigned* flag = (unsigned*)ws;                              // 16 floats reserved
    unsigned short* xh_t = (unsigned short*)(ws + 16);           // 1,280,000 sh
    unsigned short* wt   = (unsigned short*)(ws + 16 + 640000);  // 532,480 sh
    float* C  = ws + 16 + 640000 + 266240;                       // 4,128,768 fl
    unsigned short* Qb = (unsigned short*)(C + (size_t)N_ * M_ALL * P_);
    unsigned short* Kb = Qb + QTOT_;
    unsigned short* Vb = Kb + KTOT_;
    unsigned short* a_bt = Vb + VTOT_;                           // 589,824 sh

    k_detect<<<1, 64, 0, stream>>>((const unsigned*)d_in[3], flag);

    hipMemsetAsync(xh_t, 0, (size_t)N_ * PP_ * 128 * sizeof(unsigned short), stream);
    k_build_x<<<(N_ * 16 * 1152 + 255) / 256, 256, 0, stream>>>(d_in[0], d_in[3], d_in[4], xh_t, flag);
    k_copy_h<<<(N_ * 8 * P_ + 255) / 256, 256, 0, stream>>>(d_in[1], xh_t, flag);

    WPtrs wp;
    wp.p[0] = d_in[5];  wp.p[1] = d_in[6];  wp.p[2] = d_in[7];
    wp.p[3] = d_in[10]; wp.p[4] = d_in[13]; wp.p[5] = d_in[16]; wp.p[6] = d_in[19];
    wp.p[7] = d_in[9];  wp.p[8] = d_in[12]; wp.p[9] = d_in[15]; wp.p[10] = d_in[18];
    k_build_wt<<<(WCONV_ + WGATE_ + 255) / 256, 256, 0, stream>>>(wp, wt, flag);

    k_conv_mfma<<<7 * 48 * N_, 256, 0, stream>>>(xh_t, wt, C);

    k_stage_qkv<<<(QTOT_ + KTOT_ + VTOT_ + 255) / 256, 256, 0, stream>>>(C, d_in[8], Qb, Kb, Vb, flag);

    k_attn_mfma<<<36 * 16, 256, 0, stream>>>(Qb, Kb, Vb, a_bt);

    k_gate1x1<<<4 * 48 * N_, 256, 0, stream>>>(a_bt, wt + WCONV_, C);

    k_pointwise<<<(N_ * R_ * 576 + 255) / 256, 256, 0, stream>>>(C,
        d_in[11], d_in[14], d_in[17], d_in[20], d_in[2], flag, d_out);
}

// Round 9
// 136.147 us; speedup vs baseline: 1.0622x; 1.0622x over previous
//
#include <hip/hip_runtime.h>
#include <hip/hip_bf16.h>

typedef __hip_bfloat16 bf16;
typedef __attribute__((ext_vector_type(8))) short short8;
typedef __attribute__((ext_vector_type(4))) short short4v;
typedef __attribute__((ext_vector_type(4))) float f32x4;

#define N_      4
#define CI_     128
#define R_      64
#define A_      64
#define HEADS_  4
#define HD_     16
#define H_      48
#define W_      48
#define P_      (H_ * W_)      // 2304
#define HP_     50
#define PP_     (HP_ * HP_)    // 2500
#define HK_     46
#define DK_     (HK_ * HK_)    // 2116
#define M_ALL   448            // 7 conv sets x 64
#define KPAD_   2144           // 134 * 16
#define VPAD_   2176           // KPAD_ + 32 slack
#define WCONV_  516096         // 448*1152
#define WGATE_  16384          // 256*64
#define BPAD_   136            // 128 + 8 LDS pad
#define NTILE_  134            // KPAD_/16
#define TPW_    34             // ceil(134/4) key-tiles per wave
#define LOG2E_  1.44269504f

__device__ __forceinline__ float sigmoidf_(float x) { return 1.f / (1.f + __expf(-x)); }
__device__ __forceinline__ float tanh_fast(float x) {
    float e = __expf(-2.f * fabsf(x));
    float t = (1.f - e) / (1.f + e);
    return copysignf(t, x);
}
template<bool BF>
__device__ __forceinline__ float ldv(const void* p, size_t i) {
    if (BF) return __bfloat162float(((const bf16*)p)[i]);
    else    return ((const float*)p)[i];
}
__device__ __forceinline__ unsigned short f2b(float f) {
    bf16 b = __float2bfloat16(f);
    return *reinterpret_cast<unsigned short*>(&b);
}

// ---------------------------------------------------------------------------
// K0: dtype detect (bf16-packed vs fp32) from W_x bit patterns.
// ---------------------------------------------------------------------------
__global__ void k_detect(const unsigned* __restrict__ wx, unsigned* __restrict__ flag) {
    if (threadIdx.x == 0 && blockIdx.x == 0) {
        int votes = 0;
        for (int i = 0; i < 64; i++) {
            unsigned e = (wx[i] >> 7) & 0xFFu;
            votes += (e >= 100u && e <= 134u) ? 1 : 0;
        }
        *flag = (votes >= 48) ? 1u : 0u;   // 1 = bf16, 0 = fp32
    }
}

// ---------------------------------------------------------------------------
// K1a: proj_x 1x1 conv into transposed bf16 xh_t[n][pp][ci], channels 0..63.
// ---------------------------------------------------------------------------
template<bool BF>
__device__ void build_x_body(const void* __restrict__ x_in, const void* __restrict__ W_x,
                             const void* __restrict__ b_x, unsigned short* __restrict__ xh_t) {
    int idx = blockIdx.x * 256 + threadIdx.x;
    if (idx >= N_ * 16 * 1152) return;
    int pp  = idx % 1152;
    int cog = (idx / 1152) & 15;
    int n   = idx / (1152 * 16);
    int p0 = pp * 2;
    int co0 = cog * 4;

    float acc[4][2];
    #pragma unroll
    for (int j = 0; j < 4; j++) { float b = ldv<BF>(b_x, co0 + j); acc[j][0] = b; acc[j][1] = b; }

    size_t xb = (size_t)n * 128 * P_ + p0;
    #pragma unroll 4
    for (int ci = 0; ci < 128; ci++) {
        float x0 = ldv<BF>(x_in, xb + (size_t)ci * P_);
        float x1 = ldv<BF>(x_in, xb + (size_t)ci * P_ + 1);
        #pragma unroll
        for (int j = 0; j < 4; j++) {
            float w = ldv<BF>(W_x, (co0 + j) * 128 + ci);
            acc[j][0] += w * x0;
            acc[j][1] += w * x1;
        }
    }
    #pragma unroll
    for (int pi = 0; pi < 2; pi++) {
        int p = p0 + pi;
        int py = p / W_ + 1, px = p % W_ + 1;
        short4v v;
        #pragma unroll
        for (int j = 0; j < 4; j++) v[j] = (short)f2b(acc[j][pi]);
        *reinterpret_cast<short4v*>(xh_t + ((size_t)n * PP_ + py * HP_ + px) * 128 + co0) = v;
    }
}
__global__ void k_build_x(const void* x_in, const void* W_x, const void* b_x,
                          unsigned short* xh_t, const unsigned* flag) {
    if (*flag) build_x_body<true>(x_in, W_x, b_x, xh_t);
    else       build_x_body<false>(x_in, W_x, b_x, xh_t);
}

// K1b: h into xh_t channels 64..127 (8 channels per thread).
template<bool BF>
__device__ void copy_h_body(const void* __restrict__ h, unsigned short* __restrict__ xh_t) {
    int idx = blockIdx.x * 256 + threadIdx.x;
    if (idx >= N_ * 8 * P_) return;
    int p  = idx % P_;
    int cg = (idx / P_) & 7;
    int n  = idx / (P_ * 8);
    int py = p / W_ + 1, px = p % W_ + 1;
    short8 v;
    #pragma unroll
    for (int j = 0; j < 8; j++)
        v[j] = (short)f2b(ldv<BF>(h, ((size_t)n * R_ + cg * 8 + j) * P_ + p));
    *reinterpret_cast<short8*>(xh_t + ((size_t)n * PP_ + py * HP_ + px) * 128 + 64 + cg * 8) = v;
}
__global__ void k_copy_h(const void* h, unsigned short* xh_t, const unsigned* flag) {
    if (*flag) copy_h_body<true>(h, xh_t);
    else       copy_h_body<false>(h, xh_t);
}

// ---------------------------------------------------------------------------
// K1c: weights -> wt[448][9][128] bf16 (conv) + wg[256][64] bf16 (gate 1x1)
// ---------------------------------------------------------------------------
struct WPtrs { const void* p[11]; };
template<bool BF>
__device__ void build_wt_body(WPtrs wp, unsigned short* __restrict__ wt) {
    int idx = blockIdx.x * 256 + threadIdx.x;
    if (idx < WCONV_) {
        int ci  = idx % 128;
        int tap = (idx / 128) % 9;
        int m   = idx / 1152;
        int set = m >> 6, co = m & 63;
        wt[idx] = f2b(ldv<BF>(wp.p[set], (size_t)(co * 128 + ci) * 9 + tap));
    } else if (idx < WCONV_ + WGATE_) {
        int j  = idx - WCONV_;
        int ca = j & 63;
        int m  = j >> 6;          // gate*64 + r
        int gate = m >> 6, r = m & 63;
        wt[idx] = f2b(ldv<BF>(wp.p[7 + gate], r * 64 + ca));
    }
}
__global__ void k_build_wt(WPtrs wp, unsigned short* wt, const unsigned* flag) {
    if (*flag) build_wt_body<true>(wp, wt);
    else       build_wt_body<false>(wp, wt);
}

// ---------------------------------------------------------------------------
// K2: all seven 3x3 convs as one implicit GEMM, LDS-staged B.
// ---------------------------------------------------------------------------
__global__ __launch_bounds__(256) void k_conv_mfma(const unsigned short* __restrict__ xh_t,
                                                   const unsigned short* __restrict__ wt,
                                                   float* __restrict__ C) {
    __shared__ unsigned short Bs[3 * 50 * BPAD_];   // 40800 B
    int wid  = threadIdx.x >> 6;
    int lane = threadIdx.x & 63;
    int mg = blockIdx.x % 7;
    int y  = (blockIdx.x / 7) % 48;
    int n  = blockIdx.x / (7 * 48);
    int m0 = mg * 64 + wid * 16;
    int l15 = lane & 15;
    int kq  = lane >> 4;

    const unsigned short* src = xh_t + (size_t)n * PP_ * 128 + (size_t)y * HP_ * 128;
    for (int i = threadIdx.x; i < 2400; i += 256) {
        int r  = i / 800, e8 = i % 800;
        int px = e8 >> 4, cig = e8 & 15;
        short8 v = *reinterpret_cast<const short8*>(src + r * 6400 + e8 * 8);
        *reinterpret_cast<short8*>(Bs + (r * HP_ + px) * BPAD_ + cig * 8) = v;
    }
    __syncthreads();

    f32x4 acc[3] = {f32x4{0,0,0,0}, f32x4{0,0,0,0}, f32x4{0,0,0,0}};
    const unsigned short* Arow = wt + (size_t)(m0 + l15) * 1152 + kq * 8;

    #pragma unroll
    for (int r = 0; r < 3; r++) {
        #pragma unroll
        for (int c = 0; c < 3; c++) {
            int tap = r * 3 + c;
            short8 a8[4];
            #pragma unroll
            for (int cb = 0; cb < 4; cb++)
                a8[cb] = *reinterpret_cast<const short8*>(Arow + tap * 128 + cb * 32);
            #pragma unroll
            for (int cb = 0; cb < 4; cb++) {
                #pragma unroll
                for (int nf = 0; nf < 3; nf++) {
                    short8 b8 = *reinterpret_cast<const short8*>(
                        Bs + (size_t)(r * HP_ + c + nf * 16 + l15) * BPAD_ + cb * 32 + kq * 8);
                    acc[nf] = __builtin_amdgcn_mfma_f32_16x16x32_bf16(a8[cb], b8, acc[nf], 0, 0, 0);
                }
            }
        }
    }
    #pragma unroll
    for (int nf = 0; nf < 3; nf++) {
        int p = y * 48 + nf * 16 + l15;
        #pragma unroll
        for (int reg = 0; reg < 4; reg++) {
            int m = m0 + kq * 4 + reg;
            C[((size_t)n * M_ALL + m) * P_ + p] = acc[nf][reg];
        }
    }
}

// ---------------------------------------------------------------------------
// K2b: stage Q/K/V for MFMA attention as bf16. Q pre-scaled by log2(e) so
//      the attention kernel can use exp2 directly.
// ---------------------------------------------------------------------------
#define QTOT_ (16 * 2304 * 16)
#define KTOT_ (16 * KPAD_ * 16)
#define VTOT_ (16 * 16 * VPAD_)
template<bool BF>
__device__ void stage_body(const float* __restrict__ C, const void* __restrict__ b_v,
                           unsigned short* __restrict__ Qb, unsigned short* __restrict__ Kb,
                           unsigned short* __restrict__ Vb) {
    int idx = blockIdx.x * 256 + threadIdx.x;
    if (idx < QTOT_) {
        int c = idx & 15, qp = (idx >> 4) % 2304, ng = idx / (2304 * 16);
        int n = ng >> 2, g = ng & 3;
        Qb[idx] = f2b(C[((size_t)n * M_ALL + g * HD_ + c) * P_ + qp] * LOG2E_);
    } else if (idx < QTOT_ + KTOT_) {
        int i = idx - QTOT_;
        int c = i & 15, key = (i >> 4) % KPAD_, ng = i / (KPAD_ * 16);
        int n = ng >> 2, g = ng & 3;
        float v = 0.f;
        if (key < DK_)
            v = C[((size_t)n * M_ALL + 64 + g * HD_ + c) * P_ + (key / HK_ + 1) * 48 + key % HK_ + 1];
        Kb[i] = f2b(v);
    } else if (idx < QTOT_ + KTOT_ + VTOT_) {
        int i = idx - QTOT_ - KTOT_;
        int key = i % VPAD_, c = (i / VPAD_) & 15, ng = i / (VPAD_ * 16);
        int n = ng >> 2, g = ng & 3;
        float v = 0.f;
        if (key < DK_)
            v = C[((size_t)n * M_ALL + 128 + g * HD_ + c) * P_ + (key / HK_ + 1) * 48 + key % HK_ + 1]
                + ldv<BF>(b_v, g * HD_ + c);
        Vb[i] = f2b(v);
    }
}
__global__ void k_stage_qkv(const float* C, const void* b_v, unsigned short* Qb,
                            unsigned short* Kb, unsigned short* Vb, const unsigned* flag) {
    if (*flag) stage_body<true>(C, b_v, Qb, Kb, Vb);
    else       stage_body<false>(C, b_v, Qb, Kb, Vb);
}

// ---------------------------------------------------------------------------
// K3: MFMA flash attention, 16x16x16 bf16, 4-way key-split per block.
//     Block = (qt, ng): one 16-query tile. Wave w handles key-tiles
//     [w*34, min(w*34+34,134)); partial (acc[4], l) -> LDS -> wave 0 combines,
//     normalizes (exp2 domain, -28 pad correction), stores a_bt.
// ---------------------------------------------------------------------------
__global__ __launch_bounds__(256) void k_attn_mfma(const unsigned short* __restrict__ Qb,
                                                   const unsigned short* __restrict__ Kb,
                                                   const unsigned short* __restrict__ Vb,
                                                   unsigned short* __restrict__ a_bt) {
    __shared__ float red[4][64][5];
    int wid  = threadIdx.x >> 6;
    int lane = threadIdx.x & 63;
    int ng = blockIdx.x & 15;
    int qt = blockIdx.x >> 4;            // 0..143
    int l15 = lane & 15;
    int g4  = lane >> 4;

    // B-frag (QK): Q[q=l15][ch=g4*4+j], pre-scaled by log2(e)
    short4v qfrag = *reinterpret_cast<const short4v*>(
        Qb + ((size_t)ng * 2304 + qt * 16 + l15) * 16 + g4 * 4);
    const unsigned short* Kp = Kb + ((size_t)ng * KPAD_ + l15) * 16 + g4 * 4;
    const unsigned short* Vp = Vb + ((size_t)ng * 16 + l15) * VPAD_ + g4 * 4;

    f32x4 accA = {0, 0, 0, 0}, accB = {0, 0, 0, 0};
    float lp = 0.f;
    int t0 = wid * TPW_;
    int t1 = min(t0 + TPW_, NTILE_);

    #pragma unroll 2
    for (int t = t0; t < t1; t++) {
        // A-frag (QK): K[key=t*16+l15][ch=g4*4+j]
        short4v kfrag = *reinterpret_cast<const short4v*>(Kp + t * 256);
        f32x4 s = __builtin_amdgcn_mfma_f32_16x16x16bf16_1k(kfrag, qfrag, f32x4{0, 0, 0, 0}, 0, 0, 0);
        f32x4 p;
        short4v pb;
        #pragma unroll
        for (int r = 0; r < 4; r++) { p[r] = __builtin_amdgcn_exp2f(s[r]); pb[r] = (short)f2b(p[r]); }
        lp += p[0] + p[1] + p[2] + p[3];
        // A-frag (PV): V^T[c=l15][key=t*16+g4*4+j]; B-frag = pb (in-lane).
        short4v vfrag = *reinterpret_cast<const short4v*>(Vp + t * 16);
        if (t & 1) accB = __builtin_amdgcn_mfma_f32_16x16x16bf16_1k(vfrag, pb, accB, 0, 0, 0);
        else       accA = __builtin_amdgcn_mfma_f32_16x16x16bf16_1k(vfrag, pb, accA, 0, 0, 0);
    }

    #pragma unroll
    for (int r = 0; r < 4; r++) red[wid][lane][r] = accA[r] + accB[r];
    red[wid][lane][4] = lp;
    __syncthreads();
    if (wid != 0) return;

    float tot[5];
    #pragma unroll
    for (int j = 0; j < 5; j++)
        tot[j] = red[0][lane][j] + red[1][lane][j] + red[2][lane][j] + red[3][lane][j];

    float l = tot[4] + __shfl_xor(tot[4], 16);
    l += __shfl_xor(l, 32);
    l -= 28.f;                 // KPAD_-DK_ zero-keys contribute exp2(0)=1 each
    float inv = 1.f / l;

    int n = ng >> 2, g = ng & 3;
    short4v ov;
    #pragma unroll
    for (int r = 0; r < 4; r++) ov[r] = (short)f2b(tot[r] * inv);
    *reinterpret_cast<short4v*>(a_bt + ((size_t)n * 2304 + qt * 16 + l15) * 64 + g * HD_ + g4 * 4) = ov;
}

// ---------------------------------------------------------------------------
// K3c: gate 1x1 conv (M=256, K=64) via MFMA, accumulated onto C rows 192..447.
// ---------------------------------------------------------------------------
__global__ __launch_bounds__(256) void k_gate1x1(const unsigned short* __restrict__ a_bt,
                                                 const unsigned short* __restrict__ wg,
                                                 float* __restrict__ C) {
    int wid  = threadIdx.x >> 6;
    int lane = threadIdx.x & 63;
    int mg = blockIdx.x & 3;
    int y  = (blockIdx.x >> 2) % 48;
    int n  = blockIdx.x / (4 * 48);
    int m0 = mg * 64 + wid * 16;
    int l15 = lane & 15;
    int kq  = lane >> 4;

    f32x4 acc[3] = {f32x4{0,0,0,0}, f32x4{0,0,0,0}, f32x4{0,0,0,0}};
    const unsigned short* Ar = wg + (size_t)(m0 + l15) * 64 + kq * 8;
    const unsigned short* Br = a_bt + ((size_t)n * 2304 + y * 48) * 64 + kq * 8;

    #pragma unroll
    for (int ks = 0; ks < 2; ks++) {
        short8 a8 = *reinterpret_cast<const short8*>(Ar + ks * 32);
        #pragma unroll
        for (int nf = 0; nf < 3; nf++) {
            short8 b8 = *reinterpret_cast<const short8*>(Br + (size_t)(nf * 16 + l15) * 64 + ks * 32);
            acc[nf] = __builtin_amdgcn_mfma_f32_16x16x32_bf16(a8, b8, acc[nf], 0, 0, 0);
        }
    }
    #pragma unroll
    for (int nf = 0; nf < 3; nf++) {
        int p = y * 48 + nf * 16 + l15;
        #pragma unroll
        for (int reg = 0; reg < 4; reg++) {
            int m = m0 + kq * 4 + reg;
            size_t ci = ((size_t)n * M_ALL + 192 + m) * P_ + p;
            C[ci] += acc[nf][reg];
        }
    }
}

// ---------------------------------------------------------------------------
// K4: pure pointwise LSTM. 4 pixels per thread, vectorized.
// ---------------------------------------------------------------------------
template<bool BF>
__device__ void pointwise_body(const float* __restrict__ C,
                               const void* bi, const void* bf_, const void* bg, const void* bo,
                               const void* c_in, void* __restrict__ h_out) {
    int idx = blockIdx.x * 256 + threadIdx.x;
    if (idx >= N_ * R_ * 576) return;
    int p4 = idx % 576;
    int r  = (idx / 576) & 63;
    int n  = idx / (576 * 64);
    int p0 = p4 * 4;

    const float* base = C + ((size_t)n * M_ALL + 192 + r) * P_ + p0;
    float4 vi = *reinterpret_cast<const float4*>(base);
    float4 vf = *reinterpret_cast<const float4*>(base + (size_t)64 * P_);
    float4 vg = *reinterpret_cast<const float4*>(base + (size_t)128 * P_);
    float4 vo = *reinterpret_cast<const float4*>(base + (size_t)192 * P_);
    float bii = ldv<BF>(bi, r), bff = ldv<BF>(bf_, r);
    float bgg = ldv<BF>(bg, r), boo = ldv<BF>(bo, r);

    size_t cbase = ((size_t)n * R_ + r) * P_ + p0;
    float hi[4];
    #pragma unroll
    for (int j = 0; j < 4; j++) {
        float ai = (j == 0 ? vi.x : j == 1 ? vi.y : j == 2 ? vi.z : vi.w) + bii;
        float af = (j == 0 ? vf.x : j == 1 ? vf.y : j == 2 ? vf.z : vf.w) + bff;
        float ag = (j == 0 ? vg.x : j == 1 ? vg.y : j == 2 ? vg.z : vg.w) + bgg;
        float ao = (j == 0 ? vo.x : j == 1 ? vo.y : j == 2 ? vo.z : vo.w) + boo;
        float ig = sigmoidf_(ai);
        float fg = sigmoidf_(af);
        float gg = tanh_fast(ag);
        float og = sigmoidf_(ao);
        float cn = fg * ldv<BF>(c_in, cbase + j) + ig * gg;
        hi[j] = og * tanh_fast(cn);
    }
    if (BF) {
        short4v ov;
        #pragma unroll
        for (int j = 0; j < 4; j++) ov[j] = (short)f2b(hi[j]);
        *reinterpret_cast<short4v*>((bf16*)h_out + cbase) = ov;
    } else {
        float4 ov = {hi[0], hi[1], hi[2], hi[3]};
        *reinterpret_cast<float4*>((float*)h_out + cbase) = ov;
    }
}
__global__ void k_pointwise(const float* C, const void* bi, const void* bf_,
                            const void* bg, const void* bo, const void* c_in,
                            const unsigned* flag, void* h_out) {
    if (*flag) pointwise_body<true>(C, bi, bf_, bg, bo, c_in, h_out);
    else       pointwise_body<false>(C, bi, bf_, bg, bo, c_in, h_out);
}

// ---------------------------------------------------------------------------
extern "C" void kernel_launch(void* const* d_in, const int* in_sizes, int n_in,
                              void* d_out, int out_size, void* d_ws, size_t ws_size,
                              hipStream_t stream) {
    float* ws = (float*)d_ws;
    unsigned* flag = (unsigned*)ws;                              // 16 floats reserved
    unsigned short* xh_t = (unsigned short*)(ws + 16);           // 1,280,000 sh
    unsigned short* wt   = (unsigned short*)(ws + 16 + 640000);  // 532,480 sh
    float* C  = ws + 16 + 640000 + 266240;                       // 4,128,768 fl
    unsigned short* Qb = (unsigned short*)(C + (size_t)N_ * M_ALL * P_);
    unsigned short* Kb = Qb + QTOT_;
    unsigned short* Vb = Kb + KTOT_;
    unsigned short* a_bt = Vb + VTOT_;                           // 589,824 sh

    k_detect<<<1, 64, 0, stream>>>((const unsigned*)d_in[3], flag);

    (void)hipMemsetAsync(xh_t, 0, (size_t)N_ * PP_ * 128 * sizeof(unsigned short), stream);
    k_build_x<<<(N_ * 16 * 1152 + 255) / 256, 256, 0, stream>>>(d_in[0], d_in[3], d_in[4], xh_t, flag);
    k_copy_h<<<(N_ * 8 * P_ + 255) / 256, 256, 0, stream>>>(d_in[1], xh_t, flag);

    WPtrs wp;
    wp.p[0] = d_in[5];  wp.p[1] = d_in[6];  wp.p[2] = d_in[7];
    wp.p[3] = d_in[10]; wp.p[4] = d_in[13]; wp.p[5] = d_in[16]; wp.p[6] = d_in[19];
    wp.p[7] = d_in[9];  wp.p[8] = d_in[12]; wp.p[9] = d_in[15]; wp.p[10] = d_in[18];
    k_build_wt<<<(WCONV_ + WGATE_ + 255) / 256, 256, 0, stream>>>(wp, wt, flag);

    k_conv_mfma<<<7 * 48 * N_, 256, 0, stream>>>(xh_t, wt, C);

    k_stage_qkv<<<(QTOT_ + KTOT_ + VTOT_ + 255) / 256, 256, 0, stream>>>(C, d_in[8], Qb, Kb, Vb, flag);

    k_attn_mfma<<<144 * 16, 256, 0, stream>>>(Qb, Kb, Vb, a_bt);

    k_gate1x1<<<4 * 48 * N_, 256, 0, stream>>>(a_bt, wt + WCONV_, C);

    k_pointwise<<<(N_ * R_ * 576 + 255) / 256, 256, 0, stream>>>(C,
        d_in[11], d_in[14], d_in[17], d_in[20], d_in[2], flag, d_out);
}

// Round 10
// 116.566 us; speedup vs baseline: 1.2406x; 1.1680x over previous
//
#include <hip/hip_runtime.h>
#include <hip/hip_bf16.h>

typedef __hip_bfloat16 bf16;
typedef __attribute__((ext_vector_type(8))) short short8;
typedef __attribute__((ext_vector_type(4))) short short4v;
typedef __attribute__((ext_vector_type(4))) float f32x4;

#define N_      4
#define CI_     128
#define R_      64
#define A_      64
#define HEADS_  4
#define HD_     16
#define H_      48
#define W_      48
#define P_      (H_ * W_)      // 2304
#define HP_     50
#define PP_     (HP_ * HP_)    // 2500
#define HK_     46
#define DK_     (HK_ * HK_)    // 2116
#define CG_     256            // gate rows of C (4 gates x 64)
#define KPAD_   2144           // 134 * 16
#define VPAD_   2176           // KPAD_ + 32 slack
#define WCONV_  516096         // 448*1152
#define WGATE_  16384          // 256*64
#define BPAD_   136            // 128 + 8 LDS pad
#define NTILE_  134            // KPAD_/16
#define TPW_    34             // ceil(134/4) key-tiles per wave
#define LOG2E_  1.44269504f
#define QTOT_   (16 * 2304 * 16)
#define KTOT_   (16 * KPAD_ * 16)
#define VTOT_   (16 * 16 * VPAD_)

__device__ __forceinline__ float sigmoidf_(float x) { return 1.f / (1.f + __expf(-x)); }
__device__ __forceinline__ float tanh_fast(float x) {
    float e = __expf(-2.f * fabsf(x));
    float t = (1.f - e) / (1.f + e);
    return copysignf(t, x);
}
template<bool BF>
__device__ __forceinline__ float ldv(const void* p, size_t i) {
    if (BF) return __bfloat162float(((const bf16*)p)[i]);
    else    return ((const float*)p)[i];
}
__device__ __forceinline__ float ldrt(const void* p, size_t i, bool bf) {
    return bf ? __bfloat162float(((const bf16*)p)[i]) : ((const float*)p)[i];
}
__device__ __forceinline__ unsigned short f2b(float f) {
    bf16 b = __float2bfloat16(f);
    return *reinterpret_cast<unsigned short*>(&b);
}

// ---------------------------------------------------------------------------
// K0: dtype detect (bf16-packed vs fp32) from W_x bit patterns.
// ---------------------------------------------------------------------------
__global__ void k_detect(const unsigned* __restrict__ wx, unsigned* __restrict__ flag) {
    if (threadIdx.x == 0 && blockIdx.x == 0) {
        int votes = 0;
        for (int i = 0; i < 64; i++) {
            unsigned e = (wx[i] >> 7) & 0xFFu;
            votes += (e >= 100u && e <= 134u) ? 1 : 0;
        }
        *flag = (votes >= 48) ? 1u : 0u;   // 1 = bf16, 0 = fp32
    }
}

// ---------------------------------------------------------------------------
// K1a: proj_x 1x1 conv into transposed bf16 xh_t[n][pp][ci], channels 0..63.
// ---------------------------------------------------------------------------
template<bool BF>
__device__ void build_x_body(const void* __restrict__ x_in, const void* __restrict__ W_x,
                             const void* __restrict__ b_x, unsigned short* __restrict__ xh_t) {
    int idx = blockIdx.x * 256 + threadIdx.x;
    if (idx >= N_ * 16 * 1152) return;
    int pp  = idx % 1152;
    int cog = (idx / 1152) & 15;
    int n   = idx / (1152 * 16);
    int p0 = pp * 2;
    int co0 = cog * 4;

    float acc[4][2];
    #pragma unroll
    for (int j = 0; j < 4; j++) { float b = ldv<BF>(b_x, co0 + j); acc[j][0] = b; acc[j][1] = b; }

    size_t xb = (size_t)n * 128 * P_ + p0;
    #pragma unroll 4
    for (int ci = 0; ci < 128; ci++) {
        float x0 = ldv<BF>(x_in, xb + (size_t)ci * P_);
        float x1 = ldv<BF>(x_in, xb + (size_t)ci * P_ + 1);
        #pragma unroll
        for (int j = 0; j < 4; j++) {
            float w = ldv<BF>(W_x, (co0 + j) * 128 + ci);
            acc[j][0] += w * x0;
            acc[j][1] += w * x1;
        }
    }
    #pragma unroll
    for (int pi = 0; pi < 2; pi++) {
        int p = p0 + pi;
        int py = p / W_ + 1, px = p % W_ + 1;
        short4v v;
        #pragma unroll
        for (int j = 0; j < 4; j++) v[j] = (short)f2b(acc[j][pi]);
        *reinterpret_cast<short4v*>(xh_t + ((size_t)n * PP_ + py * HP_ + px) * 128 + co0) = v;
    }
}
__global__ void k_build_x(const void* x_in, const void* W_x, const void* b_x,
                          unsigned short* xh_t, const unsigned* flag) {
    if (*flag) build_x_body<true>(x_in, W_x, b_x, xh_t);
    else       build_x_body<false>(x_in, W_x, b_x, xh_t);
}

// K1b: h into xh_t channels 64..127 (8 channels per thread).
template<bool BF>
__device__ void copy_h_body(const void* __restrict__ h, unsigned short* __restrict__ xh_t) {
    int idx = blockIdx.x * 256 + threadIdx.x;
    if (idx >= N_ * 8 * P_) return;
    int p  = idx % P_;
    int cg = (idx / P_) & 7;
    int n  = idx / (P_ * 8);
    int py = p / W_ + 1, px = p % W_ + 1;
    short8 v;
    #pragma unroll
    for (int j = 0; j < 8; j++)
        v[j] = (short)f2b(ldv<BF>(h, ((size_t)n * R_ + cg * 8 + j) * P_ + p));
    *reinterpret_cast<short8*>(xh_t + ((size_t)n * PP_ + py * HP_ + px) * 128 + 64 + cg * 8) = v;
}
__global__ void k_copy_h(const void* h, unsigned short* xh_t, const unsigned* flag) {
    if (*flag) copy_h_body<true>(h, xh_t);
    else       copy_h_body<false>(h, xh_t);
}

// ---------------------------------------------------------------------------
// K1c: weights -> wt[448][9][128] bf16 (conv) + wg[256][64] bf16 (gate 1x1)
// ---------------------------------------------------------------------------
struct WPtrs { const void* p[11]; };
template<bool BF>
__device__ void build_wt_body(WPtrs wp, unsigned short* __restrict__ wt) {
    int idx = blockIdx.x * 256 + threadIdx.x;
    if (idx < WCONV_) {
        int ci  = idx % 128;
        int tap = (idx / 128) % 9;
        int m   = idx / 1152;
        int set = m >> 6, co = m & 63;
        wt[idx] = f2b(ldv<BF>(wp.p[set], (size_t)(co * 128 + ci) * 9 + tap));
    } else if (idx < WCONV_ + WGATE_) {
        int j  = idx - WCONV_;
        int ca = j & 63;
        int m  = j >> 6;          // gate*64 + r
        int gate = m >> 6, r = m & 63;
        wt[idx] = f2b(ldv<BF>(wp.p[7 + gate], r * 64 + ca));
    }
}
__global__ void k_build_wt(WPtrs wp, unsigned short* wt, const unsigned* flag) {
    if (*flag) build_wt_body<true>(wp, wt);
    else       build_wt_body<false>(wp, wt);
}

// ---------------------------------------------------------------------------
// K2: all seven 3x3 convs as one implicit GEMM, LDS-staged B.
//     Epilogue: mg=0 -> Qb (x log2e), mg=1 -> Kb, mg=2 -> Vb (+b_v),
//               mg=3..6 -> C gate rows (fp32). g = wid, c = kq*4+reg.
// ---------------------------------------------------------------------------
__global__ __launch_bounds__(256) void k_conv_mfma(const unsigned short* __restrict__ xh_t,
                                                   const unsigned short* __restrict__ wt,
                                                   float* __restrict__ C,
                                                   unsigned short* __restrict__ Qb,
                                                   unsigned short* __restrict__ Kb,
                                                   unsigned short* __restrict__ Vb,
                                                   const void* __restrict__ b_v,
                                                   const unsigned* __restrict__ flag) {
    __shared__ unsigned short Bs[3 * 50 * BPAD_];   // 40800 B
    int wid  = threadIdx.x >> 6;
    int lane = threadIdx.x & 63;
    int mg = blockIdx.x % 7;
    int y  = (blockIdx.x / 7) % 48;
    int n  = blockIdx.x / (7 * 48);
    int m0 = mg * 64 + wid * 16;
    int l15 = lane & 15;
    int kq  = lane >> 4;

    const unsigned short* src = xh_t + (size_t)n * PP_ * 128 + (size_t)y * HP_ * 128;
    for (int i = threadIdx.x; i < 2400; i += 256) {
        int r  = i / 800, e8 = i % 800;
        int px = e8 >> 4, cig = e8 & 15;
        short8 v = *reinterpret_cast<const short8*>(src + r * 6400 + e8 * 8);
        *reinterpret_cast<short8*>(Bs + (r * HP_ + px) * BPAD_ + cig * 8) = v;
    }
    __syncthreads();

    f32x4 acc[3] = {f32x4{0,0,0,0}, f32x4{0,0,0,0}, f32x4{0,0,0,0}};
    const unsigned short* Arow = wt + (size_t)(m0 + l15) * 1152 + kq * 8;

    #pragma unroll
    for (int r = 0; r < 3; r++) {
        #pragma unroll
        for (int c = 0; c < 3; c++) {
            int tap = r * 3 + c;
            short8 a8[4];
            #pragma unroll
            for (int cb = 0; cb < 4; cb++)
                a8[cb] = *reinterpret_cast<const short8*>(Arow + tap * 128 + cb * 32);
            #pragma unroll
            for (int cb = 0; cb < 4; cb++) {
                #pragma unroll
                for (int nf = 0; nf < 3; nf++) {
                    short8 b8 = *reinterpret_cast<const short8*>(
                        Bs + (size_t)(r * HP_ + c + nf * 16 + l15) * BPAD_ + cb * 32 + kq * 8);
                    acc[nf] = __builtin_amdgcn_mfma_f32_16x16x32_bf16(a8[cb], b8, acc[nf], 0, 0, 0);
                }
            }
        }
    }

    if (mg >= 3) {
        // gate pre-activations -> C rows (mg-3)*64 + wid*16 + kq*4 + reg
        #pragma unroll
        for (int nf = 0; nf < 3; nf++) {
            int p = y * 48 + nf * 16 + l15;
            #pragma unroll
            for (int reg = 0; reg < 4; reg++) {
                int row = (mg - 3) * 64 + wid * 16 + kq * 4 + reg;
                C[((size_t)n * CG_ + row) * P_ + p] = acc[nf][reg];
            }
        }
    } else {
        bool isbf = (*flag != 0u);
        int g = wid;                 // head
        int ngi = n * 4 + g;
        #pragma unroll
        for (int nf = 0; nf < 3; nf++) {
            int x = nf * 16 + l15;
            int p = y * 48 + x;
            if (mg == 0) {
                short4v q4;
                #pragma unroll
                for (int reg = 0; reg < 4; reg++) q4[reg] = (short)f2b(acc[nf][reg] * LOG2E_);
                *reinterpret_cast<short4v*>(Qb + ((size_t)ngi * 2304 + p) * 16 + kq * 4) = q4;
            } else if ((unsigned)(x - 1) < 46u && (unsigned)(y - 1) < 46u) {
                int key = (y - 1) * 46 + (x - 1);
                if (mg == 1) {
                    short4v k4;
                    #pragma unroll
                    for (int reg = 0; reg < 4; reg++) k4[reg] = (short)f2b(acc[nf][reg]);
                    *reinterpret_cast<short4v*>(Kb + ((size_t)ngi * KPAD_ + key) * 16 + kq * 4) = k4;
                } else {
                    #pragma unroll
                    for (int reg = 0; reg < 4; reg++) {
                        int c = kq * 4 + reg;
                        Vb[((size_t)ngi * 16 + c) * VPAD_ + key] =
                            f2b(acc[nf][reg] + ldrt(b_v, g * 16 + c, isbf));
                    }
                }
            }
        }
    }
}

// ---------------------------------------------------------------------------
// K3: MFMA flash attention, 16x16x16 bf16, 4-way key-split, 2 q-tiles/wave,
//     explicit next-iter K/V register prefetch. Block = (qpair, ng).
// ---------------------------------------------------------------------------
__global__ __launch_bounds__(256) void k_attn_mfma(const unsigned short* __restrict__ Qb,
                                                   const unsigned short* __restrict__ Kb,
                                                   const unsigned short* __restrict__ Vb,
                                                   unsigned short* __restrict__ a_bt) {
    __shared__ float red[4][64][10];
    int wid  = threadIdx.x >> 6;
    int lane = threadIdx.x & 63;
    int ng = blockIdx.x & 15;
    int qp = blockIdx.x >> 4;            // 0..71
    int qt0 = qp * 2, qt1 = qt0 + 1;
    int l15 = lane & 15;
    int g4  = lane >> 4;

    short4v qfA = *reinterpret_cast<const short4v*>(
        Qb + ((size_t)ng * 2304 + qt0 * 16 + l15) * 16 + g4 * 4);
    short4v qfB = *reinterpret_cast<const short4v*>(
        Qb + ((size_t)ng * 2304 + qt1 * 16 + l15) * 16 + g4 * 4);
    const unsigned short* Kp = Kb + ((size_t)ng * KPAD_ + l15) * 16 + g4 * 4;
    const unsigned short* Vp = Vb + ((size_t)ng * 16 + l15) * VPAD_ + g4 * 4;

    f32x4 a0A = {0,0,0,0}, a0B = {0,0,0,0}, a1A = {0,0,0,0}, a1B = {0,0,0,0};
    float lp0 = 0.f, lp1 = 0.f;
    int t0 = wid * TPW_;
    int t1 = min(t0 + TPW_, NTILE_);

    short4v kc = *reinterpret_cast<const short4v*>(Kp + (size_t)t0 * 256);
    short4v vc = *reinterpret_cast<const short4v*>(Vp + t0 * 16);

    #pragma unroll 2
    for (int t = t0; t < t1; t++) {
        short4v kn = kc, vn = vc;
        if (t + 1 < t1) {
            kn = *reinterpret_cast<const short4v*>(Kp + (size_t)(t + 1) * 256);
            vn = *reinterpret_cast<const short4v*>(Vp + (t + 1) * 16);
        }
        f32x4 s0 = __builtin_amdgcn_mfma_f32_16x16x16bf16_1k(kc, qfA, f32x4{0,0,0,0}, 0, 0, 0);
        f32x4 s1 = __builtin_amdgcn_mfma_f32_16x16x16bf16_1k(kc, qfB, f32x4{0,0,0,0}, 0, 0, 0);
        f32x4 p0, p1;
        short4v pb0, pb1;
        #pragma unroll
        for (int r = 0; r < 4; r++) {
            p0[r] = __builtin_amdgcn_exp2f(s0[r]); pb0[r] = (short)f2b(p0[r]);
            p1[r] = __builtin_amdgcn_exp2f(s1[r]); pb1[r] = (short)f2b(p1[r]);
        }
        lp0 += (p0[0] + p0[1]) + (p0[2] + p0[3]);
        lp1 += (p1[0] + p1[1]) + (p1[2] + p1[3]);
        if (t & 1) {
            a0B = __builtin_amdgcn_mfma_f32_16x16x16bf16_1k(vc, pb0, a0B, 0, 0, 0);
            a1B = __builtin_amdgcn_mfma_f32_16x16x16bf16_1k(vc, pb1, a1B, 0, 0, 0);
        } else {
            a0A = __builtin_amdgcn_mfma_f32_16x16x16bf16_1k(vc, pb0, a0A, 0, 0, 0);
            a1A = __builtin_amdgcn_mfma_f32_16x16x16bf16_1k(vc, pb1, a1A, 0, 0, 0);
        }
        kc = kn; vc = vn;
    }

    #pragma unroll
    for (int r = 0; r < 4; r++) {
        red[wid][lane][r]     = a0A[r] + a0B[r];
        red[wid][lane][5 + r] = a1A[r] + a1B[r];
    }
    red[wid][lane][4] = lp0;
    red[wid][lane][9] = lp1;
    __syncthreads();
    if (wid != 0) return;

    float tot[10];
    #pragma unroll
    for (int j = 0; j < 10; j++)
        tot[j] = red[0][lane][j] + red[1][lane][j] + red[2][lane][j] + red[3][lane][j];

    float l0 = tot[4] + __shfl_xor(tot[4], 16);
    l0 += __shfl_xor(l0, 32);
    l0 -= 28.f;                // pad keys contribute exp2(0)=1 each
    float l1 = tot[9] + __shfl_xor(tot[9], 16);
    l1 += __shfl_xor(l1, 32);
    l1 -= 28.f;
    float i0 = 1.f / l0, i1 = 1.f / l1;

    int n = ng >> 2, g = ng & 3;
    short4v ov0, ov1;
    #pragma unroll
    for (int r = 0; r < 4; r++) {
        ov0[r] = (short)f2b(tot[r] * i0);
        ov1[r] = (short)f2b(tot[5 + r] * i1);
    }
    *reinterpret_cast<short4v*>(a_bt + ((size_t)n * 2304 + qt0 * 16 + l15) * 64 + g * HD_ + g4 * 4) = ov0;
    *reinterpret_cast<short4v*>(a_bt + ((size_t)n * 2304 + qt1 * 16 + l15) * 64 + g * HD_ + g4 * 4) = ov1;
}

// ---------------------------------------------------------------------------
// K3c: gate 1x1 conv (M=256, K=64) via MFMA, accumulated onto C.
// ---------------------------------------------------------------------------
__global__ __launch_bounds__(256) void k_gate1x1(const unsigned short* __restrict__ a_bt,
                                                 const unsigned short* __restrict__ wg,
                                                 float* __restrict__ C) {
    int wid  = threadIdx.x >> 6;
    int lane = threadIdx.x & 63;
    int mg = blockIdx.x & 3;
    int y  = (blockIdx.x >> 2) % 48;
    int n  = blockIdx.x / (4 * 48);
    int m0 = mg * 64 + wid * 16;
    int l15 = lane & 15;
    int kq  = lane >> 4;

    f32x4 acc[3] = {f32x4{0,0,0,0}, f32x4{0,0,0,0}, f32x4{0,0,0,0}};
    const unsigned short* Ar = wg + (size_t)(m0 + l15) * 64 + kq * 8;
    const unsigned short* Br = a_bt + ((size_t)n * 2304 + y * 48) * 64 + kq * 8;

    #pragma unroll
    for (int ks = 0; ks < 2; ks++) {
        short8 a8 = *reinterpret_cast<const short8*>(Ar + ks * 32);
        #pragma unroll
        for (int nf = 0; nf < 3; nf++) {
            short8 b8 = *reinterpret_cast<const short8*>(Br + (size_t)(nf * 16 + l15) * 64 + ks * 32);
            acc[nf] = __builtin_amdgcn_mfma_f32_16x16x32_bf16(a8, b8, acc[nf], 0, 0, 0);
        }
    }
    #pragma unroll
    for (int nf = 0; nf < 3; nf++) {
        int p = y * 48 + nf * 16 + l15;
        #pragma unroll
        for (int reg = 0; reg < 4; reg++) {
            int m = m0 + kq * 4 + reg;
            C[((size_t)n * CG_ + m) * P_ + p] += acc[nf][reg];
        }
    }
}

// ---------------------------------------------------------------------------
// K4: pure pointwise LSTM. 4 pixels per thread, vectorized.
// ---------------------------------------------------------------------------
template<bool BF>
__device__ void pointwise_body(const float* __restrict__ C,
                               const void* bi, const void* bf_, const void* bg, const void* bo,
                               const void* c_in, void* __restrict__ h_out) {
    int idx = blockIdx.x * 256 + threadIdx.x;
    if (idx >= N_ * R_ * 576) return;
    int p4 = idx % 576;
    int r  = (idx / 576) & 63;
    int n  = idx / (576 * 64);
    int p0 = p4 * 4;

    const float* base = C + ((size_t)n * CG_ + r) * P_ + p0;
    float4 vi = *reinterpret_cast<const float4*>(base);
    float4 vf = *reinterpret_cast<const float4*>(base + (size_t)64 * P_);
    float4 vg = *reinterpret_cast<const float4*>(base + (size_t)128 * P_);
    float4 vo = *reinterpret_cast<const float4*>(base + (size_t)192 * P_);
    float bii = ldv<BF>(bi, r), bff = ldv<BF>(bf_, r);
    float bgg = ldv<BF>(bg, r), boo = ldv<BF>(bo, r);

    size_t cbase = ((size_t)n * R_ + r) * P_ + p0;
    float hi[4];
    #pragma unroll
    for (int j = 0; j < 4; j++) {
        float ai = (j == 0 ? vi.x : j == 1 ? vi.y : j == 2 ? vi.z : vi.w) + bii;
        float af = (j == 0 ? vf.x : j == 1 ? vf.y : j == 2 ? vf.z : vf.w) + bff;
        float ag = (j == 0 ? vg.x : j == 1 ? vg.y : j == 2 ? vg.z : vg.w) + bgg;
        float ao = (j == 0 ? vo.x : j == 1 ? vo.y : j == 2 ? vo.z : vo.w) + boo;
        float ig = sigmoidf_(ai);
        float fg = sigmoidf_(af);
        float gg = tanh_fast(ag);
        float og = sigmoidf_(ao);
        float cn = fg * ldv<BF>(c_in, cbase + j) + ig * gg;
        hi[j] = og * tanh_fast(cn);
    }
    if (BF) {
        short4v ov;
        #pragma unroll
        for (int j = 0; j < 4; j++) ov[j] = (short)f2b(hi[j]);
        *reinterpret_cast<short4v*>((bf16*)h_out + cbase) = ov;
    } else {
        float4 ov = {hi[0], hi[1], hi[2], hi[3]};
        *reinterpret_cast<float4*>((float*)h_out + cbase) = ov;
    }
}
__global__ void k_pointwise(const float* C, const void* bi, const void* bf_,
                            const void* bg, const void* bo, const void* c_in,
                            const unsigned* flag, void* h_out) {
    if (*flag) pointwise_body<true>(C, bi, bf_, bg, bo, c_in, h_out);
    else       pointwise_body<false>(C, bi, bf_, bg, bo, c_in, h_out);
}

// ---------------------------------------------------------------------------
extern "C" void kernel_launch(void* const* d_in, const int* in_sizes, int n_in,
                              void* d_out, int out_size, void* d_ws, size_t ws_size,
                              hipStream_t stream) {
    float* ws = (float*)d_ws;
    unsigned* flag = (unsigned*)ws;                              // 16 floats reserved
    unsigned short* xh_t = (unsigned short*)(ws + 16);           // 1,280,000 sh
    unsigned short* wt   = (unsigned short*)(ws + 16 + 640000);  // 532,480 sh
    float* C = ws + 16 + 640000 + 266240;                        // 2,359,296 fl (gate rows)
    unsigned short* Qb = (unsigned short*)(C + (size_t)N_ * CG_ * P_);
    unsigned short* Kb = Qb + QTOT_;
    unsigned short* Vb = Kb + KTOT_;
    unsigned short* a_bt = Vb + VTOT_;                           // 589,824 sh

    k_detect<<<1, 64, 0, stream>>>((const unsigned*)d_in[3], flag);

    (void)hipMemsetAsync(xh_t, 0, (size_t)N_ * PP_ * 128 * sizeof(unsigned short), stream);
    (void)hipMemsetAsync(Kb, 0, (size_t)(KTOT_ + VTOT_) * sizeof(unsigned short), stream);

    k_build_x<<<(N_ * 16 * 1152 + 255) / 256, 256, 0, stream>>>(d_in[0], d_in[3], d_in[4], xh_t, flag);
    k_copy_h<<<(N_ * 8 * P_ + 255) / 256, 256, 0, stream>>>(d_in[1], xh_t, flag);

    WPtrs wp;
    wp.p[0] = d_in[5];  wp.p[1] = d_in[6];  wp.p[2] = d_in[7];
    wp.p[3] = d_in[10]; wp.p[4] = d_in[13]; wp.p[5] = d_in[16]; wp.p[6] = d_in[19];
    wp.p[7] = d_in[9];  wp.p[8] = d_in[12]; wp.p[9] = d_in[15]; wp.p[10] = d_in[18];
    k_build_wt<<<(WCONV_ + WGATE_ + 255) / 256, 256, 0, stream>>>(wp, wt, flag);

    k_conv_mfma<<<7 * 48 * N_, 256, 0, stream>>>(xh_t, wt, C, Qb, Kb, Vb, d_in[8], flag);

    k_attn_mfma<<<72 * 16, 256, 0, stream>>>(Qb, Kb, Vb, a_bt);

    k_gate1x1<<<4 * 48 * N_, 256, 0, stream>>>(a_bt, wt + WCONV_, C);

    k_pointwise<<<(N_ * R_ * 576 + 255) / 256, 256, 0, stream>>>(C,
        d_in[11], d_in[14], d_in[17], d_in[20], d_in[2], flag, d_out);
}

// Round 11
// 111.118 us; speedup vs baseline: 1.3015x; 1.0490x over previous
//
#include <hip/hip_runtime.h>
#include <hip/hip_bf16.h>

typedef __hip_bfloat16 bf16;
typedef __attribute__((ext_vector_type(8))) short short8;
typedef __attribute__((ext_vector_type(4))) short short4v;
typedef __attribute__((ext_vector_type(4))) float f32x4;

#define N_      4
#define CI_     128
#define R_      64
#define A_      64
#define HEADS_  4
#define HD_     16
#define H_      48
#define W_      48
#define P_      (H_ * W_)      // 2304
#define HP_     50
#define PP_     (HP_ * HP_)    // 2500
#define HK_     46
#define DK_     (HK_ * HK_)    // 2116
#define CG_     256            // gate rows of C (4 gates x 64)
#define KPAD_   2144           // 134 * 16
#define VPAD_   2176           // KPAD_ + 32 slack
#define WCONV_  516096         // 448*1152
#define WGATE_  16384          // 256*64
#define BPAD_   136            // 128 + 8 LDS pad
#define NTILE_  134            // KPAD_/16
#define TPW_    34             // ceil(134/4) key-tiles per wave
#define LOG2E_  1.44269504f
#define QTOT_   (16 * 2304 * 16)
#define KTOT_   (16 * KPAD_ * 16)
#define VTOT_   (16 * 16 * VPAD_)

__device__ __forceinline__ float sigmoidf_(float x) { return 1.f / (1.f + __expf(-x)); }
__device__ __forceinline__ float tanh_fast(float x) {
    float e = __expf(-2.f * fabsf(x));
    float t = (1.f - e) / (1.f + e);
    return copysignf(t, x);
}
template<bool BF>
__device__ __forceinline__ float ldv(const void* p, size_t i) {
    if (BF) return __bfloat162float(((const bf16*)p)[i]);
    else    return ((const float*)p)[i];
}
__device__ __forceinline__ float ldrt(const void* p, size_t i, bool bf) {
    return bf ? __bfloat162float(((const bf16*)p)[i]) : ((const float*)p)[i];
}
__device__ __forceinline__ unsigned short f2b(float f) {
    bf16 b = __float2bfloat16(f);
    return *reinterpret_cast<unsigned short*>(&b);
}

// ---------------------------------------------------------------------------
// K0: dtype detect (bf16-packed vs fp32) from W_x bit patterns.
// ---------------------------------------------------------------------------
__global__ void k_detect(const unsigned* __restrict__ wx, unsigned* __restrict__ flag) {
    if (threadIdx.x == 0 && blockIdx.x == 0) {
        int votes = 0;
        for (int i = 0; i < 64; i++) {
            unsigned e = (wx[i] >> 7) & 0xFFu;
            votes += (e >= 100u && e <= 134u) ? 1 : 0;
        }
        *flag = (votes >= 48) ? 1u : 0u;   // 1 = bf16, 0 = fp32
    }
}

// ---------------------------------------------------------------------------
// K1a: proj_x 1x1 conv into transposed bf16 xh_t[n][pp][ci], channels 0..63.
// ---------------------------------------------------------------------------
template<bool BF>
__device__ void build_x_body(const void* __restrict__ x_in, const void* __restrict__ W_x,
                             const void* __restrict__ b_x, unsigned short* __restrict__ xh_t) {
    int idx = blockIdx.x * 256 + threadIdx.x;
    if (idx >= N_ * 16 * 1152) return;
    int pp  = idx % 1152;
    int cog = (idx / 1152) & 15;
    int n   = idx / (1152 * 16);
    int p0 = pp * 2;
    int co0 = cog * 4;

    float acc[4][2];
    #pragma unroll
    for (int j = 0; j < 4; j++) { float b = ldv<BF>(b_x, co0 + j); acc[j][0] = b; acc[j][1] = b; }

    size_t xb = (size_t)n * 128 * P_ + p0;
    #pragma unroll 4
    for (int ci = 0; ci < 128; ci++) {
        float x0 = ldv<BF>(x_in, xb + (size_t)ci * P_);
        float x1 = ldv<BF>(x_in, xb + (size_t)ci * P_ + 1);
        #pragma unroll
        for (int j = 0; j < 4; j++) {
            float w = ldv<BF>(W_x, (co0 + j) * 128 + ci);
            acc[j][0] += w * x0;
            acc[j][1] += w * x1;
        }
    }
    #pragma unroll
    for (int pi = 0; pi < 2; pi++) {
        int p = p0 + pi;
        int py = p / W_ + 1, px = p % W_ + 1;
        short4v v;
        #pragma unroll
        for (int j = 0; j < 4; j++) v[j] = (short)f2b(acc[j][pi]);
        *reinterpret_cast<short4v*>(xh_t + ((size_t)n * PP_ + py * HP_ + px) * 128 + co0) = v;
    }
}
__global__ void k_build_x(const void* x_in, const void* W_x, const void* b_x,
                          unsigned short* xh_t, const unsigned* flag) {
    if (*flag) build_x_body<true>(x_in, W_x, b_x, xh_t);
    else       build_x_body<false>(x_in, W_x, b_x, xh_t);
}

// K1b: h into xh_t channels 64..127 (8 channels per thread).
template<bool BF>
__device__ void copy_h_body(const void* __restrict__ h, unsigned short* __restrict__ xh_t) {
    int idx = blockIdx.x * 256 + threadIdx.x;
    if (idx >= N_ * 8 * P_) return;
    int p  = idx % P_;
    int cg = (idx / P_) & 7;
    int n  = idx / (P_ * 8);
    int py = p / W_ + 1, px = p % W_ + 1;
    short8 v;
    #pragma unroll
    for (int j = 0; j < 8; j++)
        v[j] = (short)f2b(ldv<BF>(h, ((size_t)n * R_ + cg * 8 + j) * P_ + p));
    *reinterpret_cast<short8*>(xh_t + ((size_t)n * PP_ + py * HP_ + px) * 128 + 64 + cg * 8) = v;
}
__global__ void k_copy_h(const void* h, unsigned short* xh_t, const unsigned* flag) {
    if (*flag) copy_h_body<true>(h, xh_t);
    else       copy_h_body<false>(h, xh_t);
}

// ---------------------------------------------------------------------------
// K1c: weights -> wt[448][9][128] bf16 (conv) + wg[256][64] bf16 (gate 1x1)
// ---------------------------------------------------------------------------
struct WPtrs { const void* p[11]; };
template<bool BF>
__device__ void build_wt_body(WPtrs wp, unsigned short* __restrict__ wt) {
    int idx = blockIdx.x * 256 + threadIdx.x;
    if (idx < WCONV_) {
        int ci  = idx % 128;
        int tap = (idx / 128) % 9;
        int m   = idx / 1152;
        int set = m >> 6, co = m & 63;
        wt[idx] = f2b(ldv<BF>(wp.p[set], (size_t)(co * 128 + ci) * 9 + tap));
    } else if (idx < WCONV_ + WGATE_) {
        int j  = idx - WCONV_;
        int ca = j & 63;
        int m  = j >> 6;          // gate*64 + r
        int gate = m >> 6, r = m & 63;
        wt[idx] = f2b(ldv<BF>(wp.p[7 + gate], r * 64 + ca));
    }
}
__global__ void k_build_wt(WPtrs wp, unsigned short* wt, const unsigned* flag) {
    if (*flag) build_wt_body<true>(wp, wt);
    else       build_wt_body<false>(wp, wt);
}

// ---------------------------------------------------------------------------
// K2: all seven 3x3 convs as one implicit GEMM, LDS-staged B.
//     v3: block = (mg-PAIR, y, n); each wave owns TWO 16-row m-frags
//     (B ds_reads shared, 216 MFMA : 108 ds_read) + next-tap A prefetch.
//     pb=3 covers only mg6 (frag1 clamped to mg6, epilogue skipped).
//     Epilogue: mg=0 -> Qb (x log2e), mg=1 -> Kb, mg=2 -> Vb (+b_v),
//               mg=3..6 -> C gate rows (fp32). g = wid, c = kq*4+reg.
// ---------------------------------------------------------------------------
__global__ __launch_bounds__(256) void k_conv_mfma(const unsigned short* __restrict__ xh_t,
                                                   const unsigned short* __restrict__ wt,
                                                   float* __restrict__ C,
                                                   unsigned short* __restrict__ Qb,
                                                   unsigned short* __restrict__ Kb,
                                                   unsigned short* __restrict__ Vb,
                                                   const void* __restrict__ b_v,
                                                   const unsigned* __restrict__ flag) {
    __shared__ unsigned short Bs[3 * 50 * BPAD_];   // 40800 B
    int wid  = threadIdx.x >> 6;
    int lane = threadIdx.x & 63;
    int pb = blockIdx.x & 3;
    int y  = (blockIdx.x >> 2) % 48;
    int n  = blockIdx.x / 192;
    int l15 = lane & 15;
    int kq  = lane >> 4;

    const unsigned short* src = xh_t + (size_t)n * PP_ * 128 + (size_t)y * HP_ * 128;
    for (int i = threadIdx.x; i < 2400; i += 256) {
        int r  = i / 800, e8 = i % 800;
        int px = e8 >> 4, cig = e8 & 15;
        short8 v = *reinterpret_cast<const short8*>(src + r * 6400 + e8 * 8);
        *reinterpret_cast<short8*>(Bs + (r * HP_ + px) * BPAD_ + cig * 8) = v;
    }
    __syncthreads();

    int mg0 = pb * 2;
    int mg1 = min(pb * 2 + 1, 6);       // pb==3: clamp (duplicate, discarded)
    const unsigned short* Ar0 = wt + (size_t)(mg0 * 64 + wid * 16 + l15) * 1152 + kq * 8;
    const unsigned short* Ar1 = wt + (size_t)(mg1 * 64 + wid * 16 + l15) * 1152 + kq * 8;

    f32x4 acc[2][3] = {{f32x4{0,0,0,0}, f32x4{0,0,0,0}, f32x4{0,0,0,0}},
                       {f32x4{0,0,0,0}, f32x4{0,0,0,0}, f32x4{0,0,0,0}}};

    short8 Acur[2][4], Anext[2][4];
    #pragma unroll
    for (int cb = 0; cb < 4; cb++) {
        Acur[0][cb] = *reinterpret_cast<const short8*>(Ar0 + cb * 32);
        Acur[1][cb] = *reinterpret_cast<const short8*>(Ar1 + cb * 32);
    }

    #pragma unroll
    for (int tap = 0; tap < 9; tap++) {
        if (tap < 8) {
            #pragma unroll
            for (int cb = 0; cb < 4; cb++) {
                Anext[0][cb] = *reinterpret_cast<const short8*>(Ar0 + (tap + 1) * 128 + cb * 32);
                Anext[1][cb] = *reinterpret_cast<const short8*>(Ar1 + (tap + 1) * 128 + cb * 32);
            }
        }
        int r = tap / 3, c = tap % 3;
        #pragma unroll
        for (int cb = 0; cb < 4; cb++) {
            short8 b8[3];
            #pragma unroll
            for (int nf = 0; nf < 3; nf++)
                b8[nf] = *reinterpret_cast<const short8*>(
                    Bs + (size_t)(r * HP_ + c + nf * 16 + l15) * BPAD_ + cb * 32 + kq * 8);
            #pragma unroll
            for (int nf = 0; nf < 3; nf++) {
                acc[0][nf] = __builtin_amdgcn_mfma_f32_16x16x32_bf16(Acur[0][cb], b8[nf], acc[0][nf], 0, 0, 0);
                acc[1][nf] = __builtin_amdgcn_mfma_f32_16x16x32_bf16(Acur[1][cb], b8[nf], acc[1][nf], 0, 0, 0);
            }
        }
        #pragma unroll
        for (int cb = 0; cb < 4; cb++) {
            Acur[0][cb] = Anext[0][cb];
            Acur[1][cb] = Anext[1][cb];
        }
    }

    bool isbf = (*flag != 0u);
    #pragma unroll
    for (int f = 0; f < 2; f++) {
        if (pb == 3 && f == 1) break;   // clamped duplicate
        int mg = pb * 2 + f;
        if (mg >= 3) {
            #pragma unroll
            for (int nf = 0; nf < 3; nf++) {
                int p = y * 48 + nf * 16 + l15;
                #pragma unroll
                for (int reg = 0; reg < 4; reg++) {
                    int row = (mg - 3) * 64 + wid * 16 + kq * 4 + reg;
                    C[((size_t)n * CG_ + row) * P_ + p] = acc[f][nf][reg];
                }
            }
        } else {
            int g = wid;                 // head
            int ngi = n * 4 + g;
            #pragma unroll
            for (int nf = 0; nf < 3; nf++) {
                int x = nf * 16 + l15;
                int p = y * 48 + x;
                if (mg == 0) {
                    short4v q4;
                    #pragma unroll
                    for (int reg = 0; reg < 4; reg++) q4[reg] = (short)f2b(acc[f][nf][reg] * LOG2E_);
                    *reinterpret_cast<short4v*>(Qb + ((size_t)ngi * 2304 + p) * 16 + kq * 4) = q4;
                } else if ((unsigned)(x - 1) < 46u && (unsigned)(y - 1) < 46u) {
                    int key = (y - 1) * 46 + (x - 1);
                    if (mg == 1) {
                        short4v k4;
                        #pragma unroll
                        for (int reg = 0; reg < 4; reg++) k4[reg] = (short)f2b(acc[f][nf][reg]);
                        *reinterpret_cast<short4v*>(Kb + ((size_t)ngi * KPAD_ + key) * 16 + kq * 4) = k4;
                    } else {
                        #pragma unroll
                        for (int reg = 0; reg < 4; reg++) {
                            int c2 = kq * 4 + reg;
                            Vb[((size_t)ngi * 16 + c2) * VPAD_ + key] =
                                f2b(acc[f][nf][reg] + ldrt(b_v, g * 16 + c2, isbf));
                        }
                    }
                }
            }
        }
    }
}

// ---------------------------------------------------------------------------
// K3: MFMA flash attention, 16x16x16 bf16, 4-way key-split, 2 q-tiles/wave,
//     explicit next-iter K/V register prefetch. Block = (qpair, ng).
// ---------------------------------------------------------------------------
__global__ __launch_bounds__(256) void k_attn_mfma(const unsigned short* __restrict__ Qb,
                                                   const unsigned short* __restrict__ Kb,
                                                   const unsigned short* __restrict__ Vb,
                                                   unsigned short* __restrict__ a_bt) {
    __shared__ float red[4][64][10];
    int wid  = threadIdx.x >> 6;
    int lane = threadIdx.x & 63;
    int ng = blockIdx.x & 15;
    int qp = blockIdx.x >> 4;            // 0..71
    int qt0 = qp * 2, qt1 = qt0 + 1;
    int l15 = lane & 15;
    int g4  = lane >> 4;

    short4v qfA = *reinterpret_cast<const short4v*>(
        Qb + ((size_t)ng * 2304 + qt0 * 16 + l15) * 16 + g4 * 4);
    short4v qfB = *reinterpret_cast<const short4v*>(
        Qb + ((size_t)ng * 2304 + qt1 * 16 + l15) * 16 + g4 * 4);
    const unsigned short* Kp = Kb + ((size_t)ng * KPAD_ + l15) * 16 + g4 * 4;
    const unsigned short* Vp = Vb + ((size_t)ng * 16 + l15) * VPAD_ + g4 * 4;

    f32x4 a0A = {0,0,0,0}, a0B = {0,0,0,0}, a1A = {0,0,0,0}, a1B = {0,0,0,0};
    float lp0 = 0.f, lp1 = 0.f;
    int t0 = wid * TPW_;
    int t1 = min(t0 + TPW_, NTILE_);

    short4v kc = *reinterpret_cast<const short4v*>(Kp + (size_t)t0 * 256);
    short4v vc = *reinterpret_cast<const short4v*>(Vp + t0 * 16);

    #pragma unroll 2
    for (int t = t0; t < t1; t++) {
        short4v kn = kc, vn = vc;
        if (t + 1 < t1) {
            kn = *reinterpret_cast<const short4v*>(Kp + (size_t)(t + 1) * 256);
            vn = *reinterpret_cast<const short4v*>(Vp + (t + 1) * 16);
        }
        f32x4 s0 = __builtin_amdgcn_mfma_f32_16x16x16bf16_1k(kc, qfA, f32x4{0,0,0,0}, 0, 0, 0);
        f32x4 s1 = __builtin_amdgcn_mfma_f32_16x16x16bf16_1k(kc, qfB, f32x4{0,0,0,0}, 0, 0, 0);
        f32x4 p0, p1;
        short4v pb0, pb1;
        #pragma unroll
        for (int r = 0; r < 4; r++) {
            p0[r] = __builtin_amdgcn_exp2f(s0[r]); pb0[r] = (short)f2b(p0[r]);
            p1[r] = __builtin_amdgcn_exp2f(s1[r]); pb1[r] = (short)f2b(p1[r]);
        }
        lp0 += (p0[0] + p0[1]) + (p0[2] + p0[3]);
        lp1 += (p1[0] + p1[1]) + (p1[2] + p1[3]);
        if (t & 1) {
            a0B = __builtin_amdgcn_mfma_f32_16x16x16bf16_1k(vc, pb0, a0B, 0, 0, 0);
            a1B = __builtin_amdgcn_mfma_f32_16x16x16bf16_1k(vc, pb1, a1B, 0, 0, 0);
        } else {
            a0A = __builtin_amdgcn_mfma_f32_16x16x16bf16_1k(vc, pb0, a0A, 0, 0, 0);
            a1A = __builtin_amdgcn_mfma_f32_16x16x16bf16_1k(vc, pb1, a1A, 0, 0, 0);
        }
        kc = kn; vc = vn;
    }

    #pragma unroll
    for (int r = 0; r < 4; r++) {
        red[wid][lane][r]     = a0A[r] + a0B[r];
        red[wid][lane][5 + r] = a1A[r] + a1B[r];
    }
    red[wid][lane][4] = lp0;
    red[wid][lane][9] = lp1;
    __syncthreads();
    if (wid != 0) return;

    float tot[10];
    #pragma unroll
    for (int j = 0; j < 10; j++)
        tot[j] = red[0][lane][j] + red[1][lane][j] + red[2][lane][j] + red[3][lane][j];

    float l0 = tot[4] + __shfl_xor(tot[4], 16);
    l0 += __shfl_xor(l0, 32);
    l0 -= 28.f;                // pad keys contribute exp2(0)=1 each
    float l1 = tot[9] + __shfl_xor(tot[9], 16);
    l1 += __shfl_xor(l1, 32);
    l1 -= 28.f;
    float i0 = 1.f / l0, i1 = 1.f / l1;

    int n = ng >> 2, g = ng & 3;
    short4v ov0, ov1;
    #pragma unroll
    for (int r = 0; r < 4; r++) {
        ov0[r] = (short)f2b(tot[r] * i0);
        ov1[r] = (short)f2b(tot[5 + r] * i1);
    }
    *reinterpret_cast<short4v*>(a_bt + ((size_t)n * 2304 + qt0 * 16 + l15) * 64 + g * HD_ + g4 * 4) = ov0;
    *reinterpret_cast<short4v*>(a_bt + ((size_t)n * 2304 + qt1 * 16 + l15) * 64 + g * HD_ + g4 * 4) = ov1;
}

// ---------------------------------------------------------------------------
// K3c: gate 1x1 conv (M=256, K=64) via MFMA, accumulated onto C.
// ---------------------------------------------------------------------------
__global__ __launch_bounds__(256) void k_gate1x1(const unsigned short* __restrict__ a_bt,
                                                 const unsigned short* __restrict__ wg,
                                                 float* __restrict__ C) {
    int wid  = threadIdx.x >> 6;
    int lane = threadIdx.x & 63;
    int mg = blockIdx.x & 3;
    int y  = (blockIdx.x >> 2) % 48;
    int n  = blockIdx.x / (4 * 48);
    int m0 = mg * 64 + wid * 16;
    int l15 = lane & 15;
    int kq  = lane >> 4;

    f32x4 acc[3] = {f32x4{0,0,0,0}, f32x4{0,0,0,0}, f32x4{0,0,0,0}};
    const unsigned short* Ar = wg + (size_t)(m0 + l15) * 64 + kq * 8;
    const unsigned short* Br = a_bt + ((size_t)n * 2304 + y * 48) * 64 + kq * 8;

    #pragma unroll
    for (int ks = 0; ks < 2; ks++) {
        short8 a8 = *reinterpret_cast<const short8*>(Ar + ks * 32);
        #pragma unroll
        for (int nf = 0; nf < 3; nf++) {
            short8 b8 = *reinterpret_cast<const short8*>(Br + (size_t)(nf * 16 + l15) * 64 + ks * 32);
            acc[nf] = __builtin_amdgcn_mfma_f32_16x16x32_bf16(a8, b8, acc[nf], 0, 0, 0);
        }
    }
    #pragma unroll
    for (int nf = 0; nf < 3; nf++) {
        int p = y * 48 + nf * 16 + l15;
        #pragma unroll
        for (int reg = 0; reg < 4; reg++) {
            int m = m0 + kq * 4 + reg;
            C[((size_t)n * CG_ + m) * P_ + p] += acc[nf][reg];
        }
    }
}

// ---------------------------------------------------------------------------
// K4: pure pointwise LSTM. 4 pixels per thread, vectorized.
// ---------------------------------------------------------------------------
template<bool BF>
__device__ void pointwise_body(const float* __restrict__ C,
                               const void* bi, const void* bf_, const void* bg, const void* bo,
                               const void* c_in, void* __restrict__ h_out) {
    int idx = blockIdx.x * 256 + threadIdx.x;
    if (idx >= N_ * R_ * 576) return;
    int p4 = idx % 576;
    int r  = (idx / 576) & 63;
    int n  = idx / (576 * 64);
    int p0 = p4 * 4;

    const float* base = C + ((size_t)n * CG_ + r) * P_ + p0;
    float4 vi = *reinterpret_cast<const float4*>(base);
    float4 vf = *reinterpret_cast<const float4*>(base + (size_t)64 * P_);
    float4 vg = *reinterpret_cast<const float4*>(base + (size_t)128 * P_);
    float4 vo = *reinterpret_cast<const float4*>(base + (size_t)192 * P_);
    float bii = ldv<BF>(bi, r), bff = ldv<BF>(bf_, r);
    float bgg = ldv<BF>(bg, r), boo = ldv<BF>(bo, r);

    size_t cbase = ((size_t)n * R_ + r) * P_ + p0;
    float hi[4];
    #pragma unroll
    for (int j = 0; j < 4; j++) {
        float ai = (j == 0 ? vi.x : j == 1 ? vi.y : j == 2 ? vi.z : vi.w) + bii;
        float af = (j == 0 ? vf.x : j == 1 ? vf.y : j == 2 ? vf.z : vf.w) + bff;
        float ag = (j == 0 ? vg.x : j == 1 ? vg.y : j == 2 ? vg.z : vg.w) + bgg;
        float ao = (j == 0 ? vo.x : j == 1 ? vo.y : j == 2 ? vo.z : vo.w) + boo;
        float ig = sigmoidf_(ai);
        float fg = sigmoidf_(af);
        float gg = tanh_fast(ag);
        float og = sigmoidf_(ao);
        float cn = fg * ldv<BF>(c_in, cbase + j) + ig * gg;
        hi[j] = og * tanh_fast(cn);
    }
    if (BF) {
        short4v ov;
        #pragma unroll
        for (int j = 0; j < 4; j++) ov[j] = (short)f2b(hi[j]);
        *reinterpret_cast<short4v*>((bf16*)h_out + cbase) = ov;
    } else {
        float4 ov = {hi[0], hi[1], hi[2], hi[3]};
        *reinterpret_cast<float4*>((float*)h_out + cbase) = ov;
    }
}
__global__ void k_pointwise(const float* C, const void* bi, const void* bf_,
                            const void* bg, const void* bo, const void* c_in,
                            const unsigned* flag, void* h_out) {
    if (*flag) pointwise_body<true>(C, bi, bf_, bg, bo, c_in, h_out);
    else       pointwise_body<false>(C, bi, bf_, bg, bo, c_in, h_out);
}

// ---------------------------------------------------------------------------
extern "C" void kernel_launch(void* const* d_in, const int* in_sizes, int n_in,
                              void* d_out, int out_size, void* d_ws, size_t ws_size,
                              hipStream_t stream) {
    float* ws = (float*)d_ws;
    unsigned* flag = (unsigned*)ws;                              // 16 floats reserved
    unsigned short* xh_t = (unsigned short*)(ws + 16);           // 1,280,000 sh
    unsigned short* wt   = (unsigned short*)(ws + 16 + 640000);  // 532,480 sh
    float* C = ws + 16 + 640000 + 266240;                        // 2,359,296 fl (gate rows)
    unsigned short* Qb = (unsigned short*)(C + (size_t)N_ * CG_ * P_);
    unsigned short* Kb = Qb + QTOT_;
    unsigned short* Vb = Kb + KTOT_;
    unsigned short* a_bt = Vb + VTOT_;                           // 589,824 sh

    k_detect<<<1, 64, 0, stream>>>((const unsigned*)d_in[3], flag);

    (void)hipMemsetAsync(xh_t, 0, (size_t)N_ * PP_ * 128 * sizeof(unsigned short), stream);
    (void)hipMemsetAsync(Kb, 0, (size_t)(KTOT_ + VTOT_) * sizeof(unsigned short), stream);

    k_build_x<<<(N_ * 16 * 1152 + 255) / 256, 256, 0, stream>>>(d_in[0], d_in[3], d_in[4], xh_t, flag);
    k_copy_h<<<(N_ * 8 * P_ + 255) / 256, 256, 0, stream>>>(d_in[1], xh_t, flag);

    WPtrs wp;
    wp.p[0] = d_in[5];  wp.p[1] = d_in[6];  wp.p[2] = d_in[7];
    wp.p[3] = d_in[10]; wp.p[4] = d_in[13]; wp.p[5] = d_in[16]; wp.p[6] = d_in[19];
    wp.p[7] = d_in[9];  wp.p[8] = d_in[12]; wp.p[9] = d_in[15]; wp.p[10] = d_in[18];
    k_build_wt<<<(WCONV_ + WGATE_ + 255) / 256, 256, 0, stream>>>(wp, wt, flag);

    k_conv_mfma<<<4 * 48 * N_, 256, 0, stream>>>(xh_t, wt, C, Qb, Kb, Vb, d_in[8], flag);

    k_attn_mfma<<<72 * 16, 256, 0, stream>>>(Qb, Kb, Vb, a_bt);

    k_gate1x1<<<4 * 48 * N_, 256, 0, stream>>>(a_bt, wt + WCONV_, C);

    k_pointwise<<<(N_ * R_ * 576 + 255) / 256, 256, 0, stream>>>(C,
        d_in[11], d_in[14], d_in[17], d_in[20], d_in[2], flag, d_out);
}

// Round 12
// 107.220 us; speedup vs baseline: 1.3488x; 1.0364x over previous
//
#include <hip/hip_runtime.h>
#include <hip/hip_bf16.h>

typedef __hip_bfloat16 bf16;
typedef __attribute__((ext_vector_type(8))) short short8;
typedef __attribute__((ext_vector_type(4))) short short4v;
typedef __attribute__((ext_vector_type(4))) float f32x4;

#define N_      4
#define CI_     128
#define R_      64
#define A_      64
#define HEADS_  4
#define HD_     16
#define H_      48
#define W_      48
#define P_      (H_ * W_)      // 2304
#define HP_     50
#define PP_     (HP_ * HP_)    // 2500
#define HK_     46
#define DK_     (HK_ * HK_)    // 2116
#define CG_     256            // gate rows of C (4 gates x 64)
#define KPAD_   2144           // 134 * 16
#define VPAD_   2176           // KPAD_ + 32 slack
#define WCONV_  516096         // 448*1152
#define WGATE_  16384          // 256*64
#define BPAD_   136            // 128 + 8 LDS pad
#define NTILE_  134            // KPAD_/16
#define TPW_    34             // ceil(134/4) key-tiles per wave
#define LOG2E_  1.44269504f
#define QTOT_   (16 * 2304 * 16)
#define KTOT_   (16 * KPAD_ * 16)
#define VTOT_   (16 * 16 * VPAD_)

__device__ __forceinline__ float sigmoidf_(float x) { return 1.f / (1.f + __expf(-x)); }
__device__ __forceinline__ float tanh_fast(float x) {
    float e = __expf(-2.f * fabsf(x));
    float t = (1.f - e) / (1.f + e);
    return copysignf(t, x);
}
template<bool BF>
__device__ __forceinline__ float ldv(const void* p, size_t i) {
    if (BF) return __bfloat162float(((const bf16*)p)[i]);
    else    return ((const float*)p)[i];
}
__device__ __forceinline__ float ldrt(const void* p, size_t i, bool bf) {
    return bf ? __bfloat162float(((const bf16*)p)[i]) : ((const float*)p)[i];
}
__device__ __forceinline__ unsigned short f2b(float f) {
    bf16 b = __float2bfloat16(f);
    return *reinterpret_cast<unsigned short*>(&b);
}

// ---------------------------------------------------------------------------
// K0: dtype detect (bf16-packed vs fp32) from W_x bit patterns.
// ---------------------------------------------------------------------------
__global__ void k_detect(const unsigned* __restrict__ wx, unsigned* __restrict__ flag) {
    if (threadIdx.x == 0 && blockIdx.x == 0) {
        int votes = 0;
        for (int i = 0; i < 64; i++) {
            unsigned e = (wx[i] >> 7) & 0xFFu;
            votes += (e >= 100u && e <= 134u) ? 1 : 0;
        }
        *flag = (votes >= 48) ? 1u : 0u;   // 1 = bf16, 0 = fp32
    }
}

// ---------------------------------------------------------------------------
// K0b: zero ONLY the pad regions (replaces two 42-us fillBuffer dispatches):
//   xh_t pad pixels (196/n x 128ch), Kb keys 2116..2143, Vb keys 2116..2175.
// ---------------------------------------------------------------------------
#define ZXH_ (N_ * 196 * 16)      // short8 stores: 12544
#define ZKB_ (16 * 28 * 2)        // short8 stores: 896
#define ZVB_ (16 * 16 * 60)       // scalar stores: 15360
__global__ void k_zero_pad(unsigned short* __restrict__ xh_t,
                           unsigned short* __restrict__ Kb,
                           unsigned short* __restrict__ Vb) {
    int idx = blockIdx.x * 256 + threadIdx.x;
    const short8 z8 = {0, 0, 0, 0, 0, 0, 0, 0};
    if (idx < ZXH_) {
        int cig = idx & 15;
        int pi  = (idx >> 4) % 196;
        int n   = idx / (196 * 16);
        int pp;
        if (pi < 50)       pp = pi;                        // row 0
        else if (pi < 100) pp = 49 * 50 + (pi - 50);       // row 49
        else if (pi < 148) pp = (pi - 100 + 1) * 50;       // col 0, rows 1..48
        else               pp = (pi - 148 + 1) * 50 + 49;  // col 49, rows 1..48
        *reinterpret_cast<short8*>(xh_t + ((size_t)n * PP_ + pp) * 128 + cig * 8) = z8;
        return;
    }
    int j = idx - ZXH_;
    if (j < ZKB_) {
        int h   = j & 1;
        int key = ((j >> 1) % 28) + DK_;
        int ngi = j / (28 * 2);
        *reinterpret_cast<short8*>(Kb + ((size_t)ngi * KPAD_ + key) * 16 + h * 8) = z8;
        return;
    }
    j -= ZKB_;
    if (j < ZVB_) {
        int key = (j % 60) + DK_;
        int c   = (j / 60) & 15;
        int ngi = j / (60 * 16);
        Vb[((size_t)ngi * 16 + c) * VPAD_ + key] = 0;
    }
}

// ---------------------------------------------------------------------------
// K1a: proj_x 1x1 conv into transposed bf16 xh_t[n][pp][ci], channels 0..63.
// ---------------------------------------------------------------------------
template<bool BF>
__device__ void build_x_body(const void* __restrict__ x_in, const void* __restrict__ W_x,
                             const void* __restrict__ b_x, unsigned short* __restrict__ xh_t) {
    int idx = blockIdx.x * 256 + threadIdx.x;
    if (idx >= N_ * 16 * 1152) return;
    int pp  = idx % 1152;
    int cog = (idx / 1152) & 15;
    int n   = idx / (1152 * 16);
    int p0 = pp * 2;
    int co0 = cog * 4;

    float acc[4][2];
    #pragma unroll
    for (int j = 0; j < 4; j++) { float b = ldv<BF>(b_x, co0 + j); acc[j][0] = b; acc[j][1] = b; }

    size_t xb = (size_t)n * 128 * P_ + p0;
    #pragma unroll 4
    for (int ci = 0; ci < 128; ci++) {
        float x0 = ldv<BF>(x_in, xb + (size_t)ci * P_);
        float x1 = ldv<BF>(x_in, xb + (size_t)ci * P_ + 1);
        #pragma unroll
        for (int j = 0; j < 4; j++) {
            float w = ldv<BF>(W_x, (co0 + j) * 128 + ci);
            acc[j][0] += w * x0;
            acc[j][1] += w * x1;
        }
    }
    #pragma unroll
    for (int pi = 0; pi < 2; pi++) {
        int p = p0 + pi;
        int py = p / W_ + 1, px = p % W_ + 1;
        short4v v;
        #pragma unroll
        for (int j = 0; j < 4; j++) v[j] = (short)f2b(acc[j][pi]);
        *reinterpret_cast<short4v*>(xh_t + ((size_t)n * PP_ + py * HP_ + px) * 128 + co0) = v;
    }
}
__global__ void k_build_x(const void* x_in, const void* W_x, const void* b_x,
                          unsigned short* xh_t, const unsigned* flag) {
    if (*flag) build_x_body<true>(x_in, W_x, b_x, xh_t);
    else       build_x_body<false>(x_in, W_x, b_x, xh_t);
}

// K1b: h into xh_t channels 64..127 (8 channels per thread).
template<bool BF>
__device__ void copy_h_body(const void* __restrict__ h, unsigned short* __restrict__ xh_t) {
    int idx = blockIdx.x * 256 + threadIdx.x;
    if (idx >= N_ * 8 * P_) return;
    int p  = idx % P_;
    int cg = (idx / P_) & 7;
    int n  = idx / (P_ * 8);
    int py = p / W_ + 1, px = p % W_ + 1;
    short8 v;
    #pragma unroll
    for (int j = 0; j < 8; j++)
        v[j] = (short)f2b(ldv<BF>(h, ((size_t)n * R_ + cg * 8 + j) * P_ + p));
    *reinterpret_cast<short8*>(xh_t + ((size_t)n * PP_ + py * HP_ + px) * 128 + 64 + cg * 8) = v;
}
__global__ void k_copy_h(const void* h, unsigned short* xh_t, const unsigned* flag) {
    if (*flag) copy_h_body<true>(h, xh_t);
    else       copy_h_body<false>(h, xh_t);
}

// ---------------------------------------------------------------------------
// K1c: weights -> wt[448][9][128] bf16 (conv) + wg[256][64] bf16 (gate 1x1)
// ---------------------------------------------------------------------------
struct WPtrs { const void* p[11]; };
template<bool BF>
__device__ void build_wt_body(WPtrs wp, unsigned short* __restrict__ wt) {
    int idx = blockIdx.x * 256 + threadIdx.x;
    if (idx < WCONV_) {
        int ci  = idx % 128;
        int tap = (idx / 128) % 9;
        int m   = idx / 1152;
        int set = m >> 6, co = m & 63;
        wt[idx] = f2b(ldv<BF>(wp.p[set], (size_t)(co * 128 + ci) * 9 + tap));
    } else if (idx < WCONV_ + WGATE_) {
        int j  = idx - WCONV_;
        int ca = j & 63;
        int m  = j >> 6;          // gate*64 + r
        int gate = m >> 6, r = m & 63;
        wt[idx] = f2b(ldv<BF>(wp.p[7 + gate], r * 64 + ca));
    }
}
__global__ void k_build_wt(WPtrs wp, unsigned short* wt, const unsigned* flag) {
    if (*flag) build_wt_body<true>(wp, wt);
    else       build_wt_body<false>(wp, wt);
}

// ---------------------------------------------------------------------------
// K2: all seven 3x3 convs as one implicit GEMM, LDS-staged B.
//     Block = (mg-PAIR, y, n); each wave owns TWO 16-row m-frags
//     (B ds_reads shared, 216 MFMA : 108 ds_read) + next-tap A prefetch.
// ---------------------------------------------------------------------------
__global__ __launch_bounds__(256) void k_conv_mfma(const unsigned short* __restrict__ xh_t,
                                                   const unsigned short* __restrict__ wt,
                                                   float* __restrict__ C,
                                                   unsigned short* __restrict__ Qb,
                                                   unsigned short* __restrict__ Kb,
                                                   unsigned short* __restrict__ Vb,
                                                   const void* __restrict__ b_v,
                                                   const unsigned* __restrict__ flag) {
    __shared__ unsigned short Bs[3 * 50 * BPAD_];   // 40800 B
    int wid  = threadIdx.x >> 6;
    int lane = threadIdx.x & 63;
    int pb = blockIdx.x & 3;
    int y  = (blockIdx.x >> 2) % 48;
    int n  = blockIdx.x / 192;
    int l15 = lane & 15;
    int kq  = lane >> 4;

    const unsigned short* src = xh_t + (size_t)n * PP_ * 128 + (size_t)y * HP_ * 128;
    for (int i = threadIdx.x; i < 2400; i += 256) {
        int r  = i / 800, e8 = i % 800;
        int px = e8 >> 4, cig = e8 & 15;
        short8 v = *reinterpret_cast<const short8*>(src + r * 6400 + e8 * 8);
        *reinterpret_cast<short8*>(Bs + (r * HP_ + px) * BPAD_ + cig * 8) = v;
    }
    __syncthreads();

    int mg0 = pb * 2;
    int mg1 = min(pb * 2 + 1, 6);       // pb==3: clamp (duplicate, discarded)
    const unsigned short* Ar0 = wt + (size_t)(mg0 * 64 + wid * 16 + l15) * 1152 + kq * 8;
    const unsigned short* Ar1 = wt + (size_t)(mg1 * 64 + wid * 16 + l15) * 1152 + kq * 8;

    f32x4 acc[2][3] = {{f32x4{0,0,0,0}, f32x4{0,0,0,0}, f32x4{0,0,0,0}},
                       {f32x4{0,0,0,0}, f32x4{0,0,0,0}, f32x4{0,0,0,0}}};

    short8 Acur[2][4], Anext[2][4];
    #pragma unroll
    for (int cb = 0; cb < 4; cb++) {
        Acur[0][cb] = *reinterpret_cast<const short8*>(Ar0 + cb * 32);
        Acur[1][cb] = *reinterpret_cast<const short8*>(Ar1 + cb * 32);
    }

    #pragma unroll
    for (int tap = 0; tap < 9; tap++) {
        if (tap < 8) {
            #pragma unroll
            for (int cb = 0; cb < 4; cb++) {
                Anext[0][cb] = *reinterpret_cast<const short8*>(Ar0 + (tap + 1) * 128 + cb * 32);
                Anext[1][cb] = *reinterpret_cast<const short8*>(Ar1 + (tap + 1) * 128 + cb * 32);
            }
        }
        int r = tap / 3, c = tap % 3;
        #pragma unroll
        for (int cb = 0; cb < 4; cb++) {
            short8 b8[3];
            #pragma unroll
            for (int nf = 0; nf < 3; nf++)
                b8[nf] = *reinterpret_cast<const short8*>(
                    Bs + (size_t)(r * HP_ + c + nf * 16 + l15) * BPAD_ + cb * 32 + kq * 8);
            #pragma unroll
            for (int nf = 0; nf < 3; nf++) {
                acc[0][nf] = __builtin_amdgcn_mfma_f32_16x16x32_bf16(Acur[0][cb], b8[nf], acc[0][nf], 0, 0, 0);
                acc[1][nf] = __builtin_amdgcn_mfma_f32_16x16x32_bf16(Acur[1][cb], b8[nf], acc[1][nf], 0, 0, 0);
            }
        }
        #pragma unroll
        for (int cb = 0; cb < 4; cb++) {
            Acur[0][cb] = Anext[0][cb];
            Acur[1][cb] = Anext[1][cb];
        }
    }

    bool isbf = (*flag != 0u);
    #pragma unroll
    for (int f = 0; f < 2; f++) {
        if (pb == 3 && f == 1) break;   // clamped duplicate
        int mg = pb * 2 + f;
        if (mg >= 3) {
            #pragma unroll
            for (int nf = 0; nf < 3; nf++) {
                int p = y * 48 + nf * 16 + l15;
                #pragma unroll
                for (int reg = 0; reg < 4; reg++) {
                    int row = (mg - 3) * 64 + wid * 16 + kq * 4 + reg;
                    C[((size_t)n * CG_ + row) * P_ + p] = acc[f][nf][reg];
                }
            }
        } else {
            int g = wid;                 // head
            int ngi = n * 4 + g;
            #pragma unroll
            for (int nf = 0; nf < 3; nf++) {
                int x = nf * 16 + l15;
                int p = y * 48 + x;
                if (mg == 0) {
                    short4v q4;
                    #pragma unroll
                    for (int reg = 0; reg < 4; reg++) q4[reg] = (short)f2b(acc[f][nf][reg] * LOG2E_);
                    *reinterpret_cast<short4v*>(Qb + ((size_t)ngi * 2304 + p) * 16 + kq * 4) = q4;
                } else if ((unsigned)(x - 1) < 46u && (unsigned)(y - 1) < 46u) {
                    int key = (y - 1) * 46 + (x - 1);
                    if (mg == 1) {
                        short4v k4;
                        #pragma unroll
                        for (int reg = 0; reg < 4; reg++) k4[reg] = (short)f2b(acc[f][nf][reg]);
                        *reinterpret_cast<short4v*>(Kb + ((size_t)ngi * KPAD_ + key) * 16 + kq * 4) = k4;
                    } else {
                        #pragma unroll
                        for (int reg = 0; reg < 4; reg++) {
                            int c2 = kq * 4 + reg;
                            Vb[((size_t)ngi * 16 + c2) * VPAD_ + key] =
                                f2b(acc[f][nf][reg] + ldrt(b_v, g * 16 + c2, isbf));
                        }
                    }
                }
            }
        }
    }
}

// ---------------------------------------------------------------------------
// K3: MFMA flash attention, 16x16x16 bf16, 4-way key-split, 2 q-tiles/wave,
//     explicit next-iter K/V register prefetch. Block = (qpair, ng).
// ---------------------------------------------------------------------------
__global__ __launch_bounds__(256) void k_attn_mfma(const unsigned short* __restrict__ Qb,
                                                   const unsigned short* __restrict__ Kb,
                                                   const unsigned short* __restrict__ Vb,
                                                   unsigned short* __restrict__ a_bt) {
    __shared__ float red[4][64][10];
    int wid  = threadIdx.x >> 6;
    int lane = threadIdx.x & 63;
    int ng = blockIdx.x & 15;
    int qp = blockIdx.x >> 4;            // 0..71
    int qt0 = qp * 2, qt1 = qt0 + 1;
    int l15 = lane & 15;
    int g4  = lane >> 4;

    short4v qfA = *reinterpret_cast<const short4v*>(
        Qb + ((size_t)ng * 2304 + qt0 * 16 + l15) * 16 + g4 * 4);
    short4v qfB = *reinterpret_cast<const short4v*>(
        Qb + ((size_t)ng * 2304 + qt1 * 16 + l15) * 16 + g4 * 4);
    const unsigned short* Kp = Kb + ((size_t)ng * KPAD_ + l15) * 16 + g4 * 4;
    const unsigned short* Vp = Vb + ((size_t)ng * 16 + l15) * VPAD_ + g4 * 4;

    f32x4 a0A = {0,0,0,0}, a0B = {0,0,0,0}, a1A = {0,0,0,0}, a1B = {0,0,0,0};
    float lp0 = 0.f, lp1 = 0.f;
    int t0 = wid * TPW_;
    int t1 = min(t0 + TPW_, NTILE_);

    short4v kc = *reinterpret_cast<const short4v*>(Kp + (size_t)t0 * 256);
    short4v vc = *reinterpret_cast<const short4v*>(Vp + t0 * 16);

    #pragma unroll 2
    for (int t = t0; t < t1; t++) {
        short4v kn = kc, vn = vc;
        if (t + 1 < t1) {
            kn = *reinterpret_cast<const short4v*>(Kp + (size_t)(t + 1) * 256);
            vn = *reinterpret_cast<const short4v*>(Vp + (t + 1) * 16);
        }
        f32x4 s0 = __builtin_amdgcn_mfma_f32_16x16x16bf16_1k(kc, qfA, f32x4{0,0,0,0}, 0, 0, 0);
        f32x4 s1 = __builtin_amdgcn_mfma_f32_16x16x16bf16_1k(kc, qfB, f32x4{0,0,0,0}, 0, 0, 0);
        f32x4 p0, p1;
        short4v pb0, pb1;
        #pragma unroll
        for (int r = 0; r < 4; r++) {
            p0[r] = __builtin_amdgcn_exp2f(s0[r]); pb0[r] = (short)f2b(p0[r]);
            p1[r] = __builtin_amdgcn_exp2f(s1[r]); pb1[r] = (short)f2b(p1[r]);
        }
        lp0 += (p0[0] + p0[1]) + (p0[2] + p0[3]);
        lp1 += (p1[0] + p1[1]) + (p1[2] + p1[3]);
        if (t & 1) {
            a0B = __builtin_amdgcn_mfma_f32_16x16x16bf16_1k(vc, pb0, a0B, 0, 0, 0);
            a1B = __builtin_amdgcn_mfma_f32_16x16x16bf16_1k(vc, pb1, a1B, 0, 0, 0);
        } else {
            a0A = __builtin_amdgcn_mfma_f32_16x16x16bf16_1k(vc, pb0, a0A, 0, 0, 0);
            a1A = __builtin_amdgcn_mfma_f32_16x16x16bf16_1k(vc, pb1, a1A, 0, 0, 0);
        }
        kc = kn; vc = vn;
    }

    #pragma unroll
    for (int r = 0; r < 4; r++) {
        red[wid][lane][r]     = a0A[r] + a0B[r];
        red[wid][lane][5 + r] = a1A[r] + a1B[r];
    }
    red[wid][lane][4] = lp0;
    red[wid][lane][9] = lp1;
    __syncthreads();
    if (wid != 0) return;

    float tot[10];
    #pragma unroll
    for (int j = 0; j < 10; j++)
        tot[j] = red[0][lane][j] + red[1][lane][j] + red[2][lane][j] + red[3][lane][j];

    float l0 = tot[4] + __shfl_xor(tot[4], 16);
    l0 += __shfl_xor(l0, 32);
    l0 -= 28.f;                // pad keys contribute exp2(0)=1 each
    float l1 = tot[9] + __shfl_xor(tot[9], 16);
    l1 += __shfl_xor(l1, 32);
    l1 -= 28.f;
    float i0 = 1.f / l0, i1 = 1.f / l1;

    int n = ng >> 2, g = ng & 3;
    short4v ov0, ov1;
    #pragma unroll
    for (int r = 0; r < 4; r++) {
        ov0[r] = (short)f2b(tot[r] * i0);
        ov1[r] = (short)f2b(tot[5 + r] * i1);
    }
    *reinterpret_cast<short4v*>(a_bt + ((size_t)n * 2304 + qt0 * 16 + l15) * 64 + g * HD_ + g4 * 4) = ov0;
    *reinterpret_cast<short4v*>(a_bt + ((size_t)n * 2304 + qt1 * 16 + l15) * 64 + g * HD_ + g4 * 4) = ov1;
}

// ---------------------------------------------------------------------------
// K3c: gate 1x1 conv (M=256, K=64) via MFMA, accumulated onto C.
// ---------------------------------------------------------------------------
__global__ __launch_bounds__(256) void k_gate1x1(const unsigned short* __restrict__ a_bt,
                                                 const unsigned short* __restrict__ wg,
                                                 float* __restrict__ C) {
    int wid  = threadIdx.x >> 6;
    int lane = threadIdx.x & 63;
    int mg = blockIdx.x & 3;
    int y  = (blockIdx.x >> 2) % 48;
    int n  = blockIdx.x / (4 * 48);
    int m0 = mg * 64 + wid * 16;
    int l15 = lane & 15;
    int kq  = lane >> 4;

    f32x4 acc[3] = {f32x4{0,0,0,0}, f32x4{0,0,0,0}, f32x4{0,0,0,0}};
    const unsigned short* Ar = wg + (size_t)(m0 + l15) * 64 + kq * 8;
    const unsigned short* Br = a_bt + ((size_t)n * 2304 + y * 48) * 64 + kq * 8;

    #pragma unroll
    for (int ks = 0; ks < 2; ks++) {
        short8 a8 = *reinterpret_cast<const short8*>(Ar + ks * 32);
        #pragma unroll
        for (int nf = 0; nf < 3; nf++) {
            short8 b8 = *reinterpret_cast<const short8*>(Br + (size_t)(nf * 16 + l15) * 64 + ks * 32);
            acc[nf] = __builtin_amdgcn_mfma_f32_16x16x32_bf16(a8, b8, acc[nf], 0, 0, 0);
        }
    }
    #pragma unroll
    for (int nf = 0; nf < 3; nf++) {
        int p = y * 48 + nf * 16 + l15;
        #pragma unroll
        for (int reg = 0; reg < 4; reg++) {
            int m = m0 + kq * 4 + reg;
            C[((size_t)n * CG_ + m) * P_ + p] += acc[nf][reg];
        }
    }
}

// ---------------------------------------------------------------------------
// K4: pure pointwise LSTM. 4 pixels per thread, vectorized.
// ---------------------------------------------------------------------------
template<bool BF>
__device__ void pointwise_body(const float* __restrict__ C,
                               const void* bi, const void* bf_, const void* bg, const void* bo,
                               const void* c_in, void* __restrict__ h_out) {
    int idx = blockIdx.x * 256 + threadIdx.x;
    if (idx >= N_ * R_ * 576) return;
    int p4 = idx % 576;
    int r  = (idx / 576) & 63;
    int n  = idx / (576 * 64);
    int p0 = p4 * 4;

    const float* base = C + ((size_t)n * CG_ + r) * P_ + p0;
    float4 vi = *reinterpret_cast<const float4*>(base);
    float4 vf = *reinterpret_cast<const float4*>(base + (size_t)64 * P_);
    float4 vg = *reinterpret_cast<const float4*>(base + (size_t)128 * P_);
    float4 vo = *reinterpret_cast<const float4*>(base + (size_t)192 * P_);
    float bii = ldv<BF>(bi, r), bff = ldv<BF>(bf_, r);
    float bgg = ldv<BF>(bg, r), boo = ldv<BF>(bo, r);

    size_t cbase = ((size_t)n * R_ + r) * P_ + p0;
    float hi[4];
    #pragma unroll
    for (int j = 0; j < 4; j++) {
        float ai = (j == 0 ? vi.x : j == 1 ? vi.y : j == 2 ? vi.z : vi.w) + bii;
        float af = (j == 0 ? vf.x : j == 1 ? vf.y : j == 2 ? vf.z : vf.w) + bff;
        float ag = (j == 0 ? vg.x : j == 1 ? vg.y : j == 2 ? vg.z : vg.w) + bgg;
        float ao = (j == 0 ? vo.x : j == 1 ? vo.y : j == 2 ? vo.z : vo.w) + boo;
        float ig = sigmoidf_(ai);
        float fg = sigmoidf_(af);
        float gg = tanh_fast(ag);
        float og = sigmoidf_(ao);
        float cn = fg * ldv<BF>(c_in, cbase + j) + ig * gg;
        hi[j] = og * tanh_fast(cn);
    }
    if (BF) {
        short4v ov;
        #pragma unroll
        for (int j = 0; j < 4; j++) ov[j] = (short)f2b(hi[j]);
        *reinterpret_cast<short4v*>((bf16*)h_out + cbase) = ov;
    } else {
        float4 ov = {hi[0], hi[1], hi[2], hi[3]};
        *reinterpret_cast<float4*>((float*)h_out + cbase) = ov;
    }
}
__global__ void k_pointwise(const float* C, const void* bi, const void* bf_,
                            const void* bg, const void* bo, const void* c_in,
                            const unsigned* flag, void* h_out) {
    if (*flag) pointwise_body<true>(C, bi, bf_, bg, bo, c_in, h_out);
    else       pointwise_body<false>(C, bi, bf_, bg, bo, c_in, h_out);
}

// ---------------------------------------------------------------------------
extern "C" void kernel_launch(void* const* d_in, const int* in_sizes, int n_in,
                              void* d_out, int out_size, void* d_ws, size_t ws_size,
                              hipStream_t stream) {
    float* ws = (float*)d_ws;
    unsigned* flag = (unsigned*)ws;                              // 16 floats reserved
    unsigned short* xh_t = (unsigned short*)(ws + 16);           // 1,280,000 sh
    unsigned short* wt   = (unsigned short*)(ws + 16 + 640000);  // 532,480 sh
    float* C = ws + 16 + 640000 + 266240;                        // 2,359,296 fl (gate rows)
    unsigned short* Qb = (unsigned short*)(C + (size_t)N_ * CG_ * P_);
    unsigned short* Kb = Qb + QTOT_;
    unsigned short* Vb = Kb + KTOT_;
    unsigned short* a_bt = Vb + VTOT_;                           // 589,824 sh

    k_detect<<<1, 64, 0, stream>>>((const unsigned*)d_in[3], flag);

    k_zero_pad<<<(ZXH_ + ZKB_ + ZVB_ + 255) / 256, 256, 0, stream>>>(xh_t, Kb, Vb);

    k_build_x<<<(N_ * 16 * 1152 + 255) / 256, 256, 0, stream>>>(d_in[0], d_in[3], d_in[4], xh_t, flag);
    k_copy_h<<<(N_ * 8 * P_ + 255) / 256, 256, 0, stream>>>(d_in[1], xh_t, flag);

    WPtrs wp;
    wp.p[0] = d_in[5];  wp.p[1] = d_in[6];  wp.p[2] = d_in[7];
    wp.p[3] = d_in[10]; wp.p[4] = d_in[13]; wp.p[5] = d_in[16]; wp.p[6] = d_in[19];
    wp.p[7] = d_in[9];  wp.p[8] = d_in[12]; wp.p[9] = d_in[15]; wp.p[10] = d_in[18];
    k_build_wt<<<(WCONV_ + WGATE_ + 255) / 256, 256, 0, stream>>>(wp, wt, flag);

    k_conv_mfma<<<4 * 48 * N_, 256, 0, stream>>>(xh_t, wt, C, Qb, Kb, Vb, d_in[8], flag);

    k_attn_mfma<<<72 * 16, 256, 0, stream>>>(Qb, Kb, Vb, a_bt);

    k_gate1x1<<<4 * 48 * N_, 256, 0, stream>>>(a_bt, wt + WCONV_, C);

    k_pointwise<<<(N_ * R_ * 576 + 255) / 256, 256, 0, stream>>>(C,
        d_in[11], d_in[14], d_in[17], d_in[20], d_in[2], flag, d_out);
}